// Round 13
// baseline (844.829 us; speedup 1.0000x reference)
//
#include <hip/hip_runtime.h>

#define NNODES 20000
#define NEDGES 320000
#define HID 128
#define NL 4

constexpr int NH = NNODES * HID;
#define BN_INV (1.0f / (float)NNODES)
#define HROWS 32         // MFMA GEMM rows/block; 625 blocks

typedef unsigned short u16;
typedef unsigned int u32;
typedef unsigned long long u64;
typedef __attribute__((ext_vector_type(8))) short bf16x8;
typedef __attribute__((ext_vector_type(8))) _Float16 f16x8;
typedef __attribute__((ext_vector_type(4))) float f32x4;

// ---------------------------------------------------------------- bf16 utils
__device__ __forceinline__ float bf2f(u32 lo16) {
    union { u32 u; float f; } c; c.u = lo16 << 16; return c.f;
}
__device__ __forceinline__ u16 f2bf(float f) {
    union { float f; u32 u; } c; c.f = f;
    u32 r = c.u + 0x7FFFu + ((c.u >> 16) & 1u);
    return (u16)(r >> 16);
}
__device__ __forceinline__ u32 pack2(float a, float b) {
    return (u32)f2bf(a) | ((u32)f2bf(b) << 16);
}

// ------------------------------------------ one-time bf16 head-weight transpose
__global__ __launch_bounds__(256) void k_wt(const float* __restrict__ pw1,
    u16* __restrict__ wt)
{
    int i = blockIdx.x * 256 + threadIdx.x;          // 640 blocks
    int k = i & 127;
    int c = (i >> 7) & 127;
    int sh = i >> 14;                                // h*2+s
    wt[i] = f2bf(pw1[(size_t)(sh >> 1) * 256 * 128 + (((sh & 1) * 128 + k) << 7) + c]);
}

// ------------------------------------------ one-time fp16 MLP-weight transpose
__global__ __launch_bounds__(256) void k_wtm(const float* __restrict__ w1,
    const float* __restrict__ w2, u16* __restrict__ wtm)
{
    int i = blockIdx.x * 256 + threadIdx.x;          // 512 blocks
    int k = i & 127;
    int c = (i >> 7) & 127;
    int lw = i >> 14;                                // layer*2+which
    const float* wsrc = (lw & 1) ? w2 : w1;
    float v = wsrc[(size_t)(lw >> 1) * 16384 + (k << 7) + c];
    union { _Float16 h; u16 u; } cv; cv.h = (_Float16)v;
    wtm[i] = cv.u;
}

// ---------------------------------------------------------------- CSR build
__global__ __launch_bounds__(256) void k_hist(const int* __restrict__ dst,
    int* __restrict__ deg)
{
    int e = blockIdx.x * 256 + threadIdx.x;
    atomicAdd(&deg[dst[e]], 1);
}

__global__ __launch_bounds__(1024) void k_scan(const int* __restrict__ deg,
    int* __restrict__ off)
{
    __shared__ int part[1024];
    const int t = threadIdx.x;
    const int lo = t * 20, hi = min(lo + 20, NNODES);
    int s = 0;
    for (int i = lo; i < hi; ++i) s += deg[i];
    part[t] = s;
    __syncthreads();
    for (int d = 1; d < 1024; d <<= 1) {
        int v = (t >= d) ? part[t - d] : 0;
        __syncthreads();
        part[t] += v;
        __syncthreads();
    }
    int base = part[t] - s;
    for (int i = lo; i < hi; ++i) { off[i] = base; base += deg[i]; }
}

__global__ __launch_bounds__(256) void k_fill(const int* __restrict__ src,
    const int* __restrict__ dst, int* __restrict__ off,
    u16* __restrict__ eidx, int* __restrict__ epos)
{
    int e = blockIdx.x * 256 + threadIdx.x;
    int p = atomicAdd(&off[dst[e]], 1);
    eidx[p] = (u16)src[e];
    epos[p] = e;
}

// ---- per-node src-sort of edge segments (locality: wavefront alignment) ----
__global__ __launch_bounds__(256) void k_sortseg(const int* __restrict__ off,
    u16* __restrict__ eidx, int* __restrict__ epos)
{
    int n = blockIdx.x * 256 + threadIdx.x;          // grid 79 blocks
    if (n >= NNODES) return;
    int start = n ? off[n - 1] : 0;
    int end = off[n];
    int len = end - start;
    if (len <= 1 || len > 64) return;                // deg cap (never hit: mean 16)
    u64 buf[64];
    for (int i = 0; i < len; ++i)
        buf[i] = ((u64)eidx[start + i] << 32) | (u32)epos[start + i];
    for (int i = 1; i < len; ++i) {
        u64 key = buf[i];
        int j = i - 1;
        while (j >= 0 && buf[j] > key) { buf[j + 1] = buf[j]; --j; }
        buf[j + 1] = key;
    }
    for (int i = 0; i < len; ++i) {
        eidx[start + i] = (u16)(buf[i] >> 32);
        epos[start + i] = (int)(buf[i] & 0xffffffffu);
    }
}

// --------------------------------------------- stat helper (k_app_stat)
__device__ __forceinline__ void stat_reduce4(float* s4, float* q4, int j0,
    float* ls, float* lq, float* sums)
{
    const int lane = threadIdx.x & 63;
    #pragma unroll
    for (int c = 0; c < 4; ++c) {
        s4[c] += __shfl_xor(s4[c], 32);
        q4[c] += __shfl_xor(q4[c], 32);
    }
    if (lane < 32) {
        #pragma unroll
        for (int c = 0; c < 4; ++c) {
            atomicAdd(&ls[j0 + c], s4[c]);
            atomicAdd(&lq[j0 + c], q4[c]);
        }
    }
    __syncthreads();
    if (threadIdx.x < 128) {
        atomicAdd(&sums[threadIdx.x], ls[threadIdx.x]);
        atomicAdd(&sums[128 + threadIdx.x], lq[threadIdx.x]);
    }
}

// -------------------------------------- MFMA MLP GEMM core (single matrix)
#define MLP_MFMA_TAIL(wtm16, bias, Cm, sums)                                   \
    {                                                                          \
    const int w = tid >> 6;                                                    \
    const int lane = tid & 63;                                                 \
    const int rt = w >> 1;                                                     \
    const int cg = w & 1;                                                      \
    const int lrow = lane & 15;                                                \
    const int kgrp = lane >> 4;                                                \
    f32x4 acc[4];                                                              \
    _Pragma("unroll")                                                          \
    for (int ct = 0; ct < 4; ++ct) acc[ct] = (f32x4){0.f, 0.f, 0.f, 0.f};      \
    _Pragma("unroll")                                                          \
    for (int ks = 0; ks < 4; ++ks) {                                           \
        f16x8 a = *reinterpret_cast<const f16x8*>(                             \
            &Xs[rt * 16 + lrow][ks * 32 + kgrp * 8]);                          \
        _Pragma("unroll")                                                      \
        for (int ct = 0; ct < 4; ++ct) {                                       \
            int col = (cg * 4 + ct) * 16 + lrow;                               \
            f16x8 b = *reinterpret_cast<const f16x8*>(                         \
                wtm16 + ((size_t)col << 7) + ks * 32 + kgrp * 8);              \
            acc[ct] = __builtin_amdgcn_mfma_f32_16x16x32_f16(a, b, acc[ct], 0, 0, 0);\
        }                                                                      \
    }                                                                          \
    _Pragma("unroll")                                                          \
    for (int ct = 0; ct < 4; ++ct) {                                           \
        int col = (cg * 4 + ct) * 16 + lrow;                                   \
        float bbv = bias[col];                                                 \
        float s = 0.f, q = 0.f;                                                \
        _Pragma("unroll")                                                      \
        for (int r = 0; r < 4; ++r) {                                          \
            float val = acc[ct][r] + bbv;                                      \
            Os[rt * 16 + kgrp * 4 + r][col] = val;                             \
            s += val;                                                          \
            q = fmaf(val, val, q);                                             \
        }                                                                      \
        s += __shfl_xor(s, 16); s += __shfl_xor(s, 32);                        \
        q += __shfl_xor(q, 16); q += __shfl_xor(q, 32);                        \
        if (kgrp == 0) { atomicAdd(&ls[col], s); atomicAdd(&lq[col], q); }     \
    }                                                                          \
    __syncthreads();                                                           \
    _Pragma("unroll")                                                          \
    for (int it = 0; it < 4; ++it) {                                           \
        int f = tid + it * 256;                                                \
        int r = f >> 5, c4 = (f & 31) << 2;                                    \
        *reinterpret_cast<float4*>(Cm + (size_t)(br + r) * HID + c4) =         \
            *reinterpret_cast<const float4*>(&Os[r][c4]);                      \
    }                                                                          \
    if (tid < 128) {                                                           \
        atomicAdd(&sums[tid], ls[tid]);                                        \
        atomicAdd(&sums[128 + tid], lq[tid]);                                  \
    }                                                                          \
    }

// u = t @ W1 + b1 ; stats(u)
__global__ __launch_bounds__(256) void k_mfma_stat(const float* __restrict__ X,
    const u16* __restrict__ wtm, const float* __restrict__ bias,
    float* __restrict__ Cm, float* __restrict__ sums)
{
    __shared__ _Float16 Xs[HROWS][136];
    __shared__ float Os[HROWS][132];
    __shared__ float ls[128], lq[128];
    const int tid = threadIdx.x;
    const int br = blockIdx.x * HROWS;
    if (tid < 128) { ls[tid] = 0.f; lq[tid] = 0.f; }
    #pragma unroll
    for (int it = 0; it < 4; ++it) {
        int f = tid + it * 256;
        int r = f >> 5, kq = (f & 31) << 2;
        float4 v = *reinterpret_cast<const float4*>(X + (size_t)(br + r) * HID + kq);
        union { _Float16 h[4]; uint2 u; } p;
        p.h[0] = (_Float16)v.x; p.h[1] = (_Float16)v.y;
        p.h[2] = (_Float16)v.z; p.h[3] = (_Float16)v.w;
        *reinterpret_cast<uint2*>(&Xs[r][kq]) = p.u;
    }
    __syncthreads();
    const _Float16* wtm16 = reinterpret_cast<const _Float16*>(wtm);
    MLP_MFMA_TAIL(wtm16, bias, Cm, sums)
}

// v = relu(BN_sIn(u)) @ W2 + b2 ; stats(v)
__global__ __launch_bounds__(256) void k_mfma_bnin_stat(const float* __restrict__ X,
    const float* __restrict__ sIn, const float* __restrict__ g, const float* __restrict__ b,
    const u16* __restrict__ wtm, const float* __restrict__ bias,
    float* __restrict__ Cm, float* __restrict__ sums)
{
    __shared__ _Float16 Xs[HROWS][136];
    __shared__ float Os[HROWS][132];
    __shared__ float ac[256];
    __shared__ float ls[128], lq[128];
    const int tid = threadIdx.x;
    const int br = blockIdx.x * HROWS;
    if (tid < 128) {
        float m = sIn[tid] * BN_INV;
        float var = fmaf(-m, m, sIn[128 + tid] * BN_INV);
        float a = g[tid] * rsqrtf(var + 1e-5f);
        ac[tid] = a;
        ac[128 + tid] = fmaf(-m, a, b[tid]);
        ls[tid] = 0.f; lq[tid] = 0.f;
    }
    __syncthreads();
    #pragma unroll
    for (int it = 0; it < 4; ++it) {
        int f = tid + it * 256;
        int r = f >> 5, kq = (f & 31) << 2;
        float4 v = *reinterpret_cast<const float4*>(X + (size_t)(br + r) * HID + kq);
        float t0 = fmaxf(fmaf(ac[kq + 0], v.x, ac[128 + kq + 0]), 0.f);
        float t1 = fmaxf(fmaf(ac[kq + 1], v.y, ac[128 + kq + 1]), 0.f);
        float t2 = fmaxf(fmaf(ac[kq + 2], v.z, ac[128 + kq + 2]), 0.f);
        float t3 = fmaxf(fmaf(ac[kq + 3], v.w, ac[128 + kq + 3]), 0.f);
        union { _Float16 h[4]; uint2 u; } p;
        p.h[0] = (_Float16)t0; p.h[1] = (_Float16)t1;
        p.h[2] = (_Float16)t2; p.h[3] = (_Float16)t3;
        *reinterpret_cast<uint2*>(&Xs[r][kq]) = p.u;
    }
    __syncthreads();
    const _Float16* wtm16 = reinterpret_cast<const _Float16*>(wtm);
    MLP_MFMA_TAIL(wtm16, bias, Cm, sums)
}

// ---------------------------------------------- MFMA head GEMM core (shared)
#define HEAD_MFMA_BODY(wtbase, b1, A, Bm)                                      \
    {                                                                          \
    const int w = tid >> 6;                                                    \
    const int lane = tid & 63;                                                 \
    const int rt = w >> 1;                                                     \
    const int cg = w & 1;                                                      \
    const int lrow = lane & 15;                                                \
    const int kgrp = lane >> 4;                                                \
    const u16* wtA = wtbase;                                                   \
    const u16* wtB = wtbase + 16384;                                           \
    f32x4 accA[4], accB[4];                                                    \
    _Pragma("unroll")                                                          \
    for (int ct = 0; ct < 4; ++ct) {                                           \
        accA[ct] = (f32x4){0.f, 0.f, 0.f, 0.f};                                \
        accB[ct] = (f32x4){0.f, 0.f, 0.f, 0.f};                                \
    }                                                                          \
    _Pragma("unroll")                                                          \
    for (int ks = 0; ks < 4; ++ks) {                                           \
        bf16x8 a = *reinterpret_cast<const bf16x8*>(                           \
            &Xs[rt * 16 + lrow][ks * 32 + kgrp * 8]);                          \
        _Pragma("unroll")                                                      \
        for (int ct = 0; ct < 4; ++ct) {                                       \
            int col = (cg * 4 + ct) * 16 + lrow;                               \
            bf16x8 ba = *reinterpret_cast<const bf16x8*>(                      \
                wtA + ((size_t)col << 7) + ks * 32 + kgrp * 8);                \
            bf16x8 bb = *reinterpret_cast<const bf16x8*>(                      \
                wtB + ((size_t)col << 7) + ks * 32 + kgrp * 8);                \
            accA[ct] = __builtin_amdgcn_mfma_f32_16x16x32_bf16(a, ba, accA[ct], 0, 0, 0);\
            accB[ct] = __builtin_amdgcn_mfma_f32_16x16x32_bf16(a, bb, accB[ct], 0, 0, 0);\
        }                                                                      \
    }                                                                          \
    _Pragma("unroll")                                                          \
    for (int ct = 0; ct < 4; ++ct) {                                           \
        int col = (cg * 4 + ct) * 16 + lrow;                                   \
        float bbv = b1[col];                                                   \
        _Pragma("unroll")                                                      \
        for (int r = 0; r < 4; ++r) {                                          \
            int row = rt * 16 + kgrp * 4 + r;                                  \
            Os[0][row][col] = f2bf(accA[ct][r] + bbv);                         \
            Os[1][row][col] = f2bf(accB[ct][r]);                               \
        }                                                                      \
    }                                                                          \
    __syncthreads();                                                           \
    _Pragma("unroll")                                                          \
    for (int it = 0; it < 4; ++it) {                                           \
        int f = tid + it * 256;        /* 1024 uint4 total */                  \
        int s = f >> 9;                                                        \
        int rem = f & 511;                                                     \
        int r = rem >> 4, c8 = (rem & 15) << 3;                                \
        uint4 vv = *reinterpret_cast<uint4*>(&Os[s][r][c8]);                   \
        u16* dstp = s ? Bm : A;                                                \
        *reinterpret_cast<uint4*>(dstp + (size_t)(br + r) * HID + c8) = vv;    \
    }                                                                          \
    }

// head 0: staging computes embed x = h@emb_w+emb_b, writes x/xh, stages bf16
__global__ __launch_bounds__(256) void k_gemm_head0(const float* __restrict__ h,
    const float* __restrict__ ew, const float* __restrict__ eb,
    float* __restrict__ x, u16* __restrict__ xh,
    const u16* __restrict__ wt, const float* __restrict__ b1,
    u16* __restrict__ A, u16* __restrict__ Bm)
{
    __shared__ u16 Xs[HROWS][136];
    __shared__ u16 Os[2][HROWS][136];
    const int tid = threadIdx.x;
    const int br = blockIdx.x * HROWS;
    #pragma unroll
    for (int it = 0; it < 4; ++it) {
        int f = tid + it * 256;
        int r = f >> 5, cq = (f & 31) << 2;
        int nrow = br + r;
        float2 hv = *reinterpret_cast<const float2*>(h + nrow * 2);
        float4 w0 = *reinterpret_cast<const float4*>(ew + cq);
        float4 w1 = *reinterpret_cast<const float4*>(ew + HID + cq);
        float4 bb = *reinterpret_cast<const float4*>(eb + cq);
        float4 v;
        v.x = fmaf(hv.x, w0.x, fmaf(hv.y, w1.x, bb.x));
        v.y = fmaf(hv.x, w0.y, fmaf(hv.y, w1.y, bb.y));
        v.z = fmaf(hv.x, w0.z, fmaf(hv.y, w1.z, bb.z));
        v.w = fmaf(hv.x, w0.w, fmaf(hv.y, w1.w, bb.w));
        size_t goff = (size_t)nrow * HID + cq;
        *reinterpret_cast<float4*>(x + goff) = v;
        uint2 p = make_uint2(pack2(v.x, v.y), pack2(v.z, v.w));
        *reinterpret_cast<uint2*>(xh + goff) = p;
        *reinterpret_cast<uint2*>(&Xs[r][cq]) = p;
    }
    __syncthreads();
    HEAD_MFMA_BODY(wt, b1, A, Bm)
}

// heads 1..L: staging computes x += relu(gin(relu(app(v)))), writes x (+xh),
// stages updated x as bf16 into LDS, then MFMA dual GEMM.
__global__ __launch_bounds__(256) void k_head_resid(const float* __restrict__ v,
    const float* __restrict__ s1, const float* __restrict__ ga, const float* __restrict__ ba,
    const float* __restrict__ s2, const float* __restrict__ gg, const float* __restrict__ bg,
    float* __restrict__ x, u16* __restrict__ xh,
    const u16* __restrict__ wt, const float* __restrict__ b1,
    u16* __restrict__ A, u16* __restrict__ Bm)
{
    __shared__ u16 Xs[HROWS][136];
    __shared__ u16 Os[2][HROWS][136];
    __shared__ float aca[256], acg[256];
    const int tid = threadIdx.x;
    const int br = blockIdx.x * HROWS;
    if (tid < 128) {
        float m = s1[tid] * BN_INV;
        float var = fmaf(-m, m, s1[128 + tid] * BN_INV);
        float a = ga[tid] * rsqrtf(var + 1e-5f);
        aca[tid] = a;
        aca[128 + tid] = fmaf(-m, a, ba[tid]);
        float m2 = s2[tid] * BN_INV;
        float var2 = fmaf(-m2, m2, s2[128 + tid] * BN_INV);
        float a2 = gg[tid] * rsqrtf(var2 + 1e-5f);
        acg[tid] = a2;
        acg[128 + tid] = fmaf(-m2, a2, bg[tid]);
    }
    __syncthreads();
    #pragma unroll
    for (int it = 0; it < 4; ++it) {
        int f = tid + it * 256;
        int r = f >> 5, kq = (f & 31) << 2;
        size_t goff = (size_t)(br + r) * HID + kq;
        float4 vv = *reinterpret_cast<const float4*>(v + goff);
        float4 xv = *reinterpret_cast<const float4*>(x + goff);
        float t0 = fmaxf(fmaf(aca[kq + 0], vv.x, aca[128 + kq + 0]), 0.f);
        float t1 = fmaxf(fmaf(aca[kq + 1], vv.y, aca[128 + kq + 1]), 0.f);
        float t2 = fmaxf(fmaf(aca[kq + 2], vv.z, aca[128 + kq + 2]), 0.f);
        float t3 = fmaxf(fmaf(aca[kq + 3], vv.w, aca[128 + kq + 3]), 0.f);
        xv.x += fmaxf(fmaf(acg[kq + 0], t0, acg[128 + kq + 0]), 0.f);
        xv.y += fmaxf(fmaf(acg[kq + 1], t1, acg[128 + kq + 1]), 0.f);
        xv.z += fmaxf(fmaf(acg[kq + 2], t2, acg[128 + kq + 2]), 0.f);
        xv.w += fmaxf(fmaf(acg[kq + 3], t3, acg[128 + kq + 3]), 0.f);
        *reinterpret_cast<float4*>(x + goff) = xv;
        uint2 p = make_uint2(pack2(xv.x, xv.y), pack2(xv.z, xv.w));
        *reinterpret_cast<uint2*>(xh + goff) = p;
        *reinterpret_cast<uint2*>(&Xs[r][kq]) = p;
    }
    __syncthreads();
    HEAD_MFMA_BODY(wt, b1, A, Bm)
}

// ------------------------------------- stats of relu(app(v)) -> s2
__global__ __launch_bounds__(256) void k_app_stat(const float* __restrict__ v,
    const float* __restrict__ s1, const float* __restrict__ g, const float* __restrict__ b,
    float* __restrict__ s2)
{
    __shared__ float ac[256];
    __shared__ float ls[128], lq[128];
    const int tid = threadIdx.x;
    if (tid < 128) {
        float m = s1[tid] * BN_INV;
        float var = fmaf(-m, m, s1[128 + tid] * BN_INV);
        float a = g[tid] * rsqrtf(var + 1e-5f);
        ac[tid] = a;
        ac[128 + tid] = fmaf(-m, a, b[tid]);
        ls[tid] = 0.f; lq[tid] = 0.f;
    }
    __syncthreads();
    const int j0 = (tid & 31) * 4;
    const int row0 = blockIdx.x * 16 + (tid >> 5);
    float s4[4] = {0.f, 0.f, 0.f, 0.f}, q4[4] = {0.f, 0.f, 0.f, 0.f};
    #pragma unroll
    for (int rr = 0; rr < 2; ++rr) {
        const float4 v4 = *reinterpret_cast<const float4*>(
            v + (size_t)(row0 + rr * 8) * HID + j0);
        float w[4] = {v4.x, v4.y, v4.z, v4.w};
        #pragma unroll
        for (int c = 0; c < 4; ++c) {
            w[c] = fmaxf(fmaf(ac[j0 + c], w[c], ac[128 + j0 + c]), 0.f);
            s4[c] += w[c];
            q4[c] = fmaf(w[c], w[c], q4[c]);
        }
    }
    stat_reduce4(s4, q4, j0, ls, lq, s2);
}

// ---------------------------------------------------- edge head (dst-CSR)
__global__ __launch_bounds__(256) void k_edge_csr(const u16* __restrict__ Ah,
    const u16* __restrict__ Bh, const int* __restrict__ off,
    const u16* __restrict__ eidx, const int* __restrict__ epos,
    const float* __restrict__ w2, const float* __restrict__ b2,
    float* __restrict__ out, int accumulate)
{
    const int wid = (blockIdx.x * 256 + threadIdx.x) >> 6;
    const int lane = threadIdx.x & 63;
    const int q = lane >> 4, l = lane & 15;
    const int start = wid ? off[wid - 1] : 0;
    const int end = off[wid];
    const uint4 bb = *reinterpret_cast<const uint4*>(Bh + (size_t)wid * HID + l * 8);
    float b8[8] = {bf2f(bb.x & 0xffff), bf2f(bb.x >> 16),
                   bf2f(bb.y & 0xffff), bf2f(bb.y >> 16),
                   bf2f(bb.z & 0xffff), bf2f(bb.z >> 16),
                   bf2f(bb.w & 0xffff), bf2f(bb.w >> 16)};
    float w2f[16];
    #pragma unroll
    for (int t = 0; t < 4; ++t)
        *reinterpret_cast<float4*>(&w2f[t * 4]) =
            *reinterpret_cast<const float4*>(w2 + l * 16 + t * 4);
    const float bias0 = b2[0], bias1 = b2[1];

    #define EC_BODY(EE)                                                        \
    {                                                                          \
        int s = eidx[EE];                                                      \
        const uint4 aa = *reinterpret_cast<const uint4*>(Ah + (size_t)s * HID + l * 8);\
        float a8[8] = {bf2f(aa.x & 0xffff), bf2f(aa.x >> 16),                  \
                       bf2f(aa.y & 0xffff), bf2f(aa.y >> 16),                  \
                       bf2f(aa.z & 0xffff), bf2f(aa.z >> 16),                  \
                       bf2f(aa.w & 0xffff), bf2f(aa.w >> 16)};                 \
        float s0 = 0.f, s1 = 0.f;                                              \
        _Pragma("unroll")                                                      \
        for (int j = 0; j < 8; ++j) {                                          \
            float z = fmaxf(a8[j] + b8[j], 0.f);                               \
            s0 = fmaf(z, w2f[j * 2], s0);                                      \
            s1 = fmaf(z, w2f[j * 2 + 1], s1);                                  \
        }                                                                      \
        _Pragma("unroll")                                                      \
        for (int m = 8; m >= 1; m >>= 1) {                                     \
            s0 += __shfl_xor(s0, m);                                           \
            s1 += __shfl_xor(s1, m);                                           \
        }                                                                      \
        if (l == 0) {                                                          \
            int oe = epos[EE];                                                 \
            float o0 = s0 + bias0, o1 = s1 + bias1;                            \
            if (accumulate) { out[oe * 2] += o0; out[oe * 2 + 1] += o1; }      \
            else            { out[oe * 2]  = o0; out[oe * 2 + 1]  = o1; }      \
        }                                                                      \
    }

    int e = start + q;
    for (; e + 12 < end; e += 16) {
        EC_BODY(e) EC_BODY(e + 4) EC_BODY(e + 8) EC_BODY(e + 12)
    }
    for (; e < end; e += 4) EC_BODY(e)
    #undef EC_BODY
}

// ------------------------- merged edge head + gather (one CSR pass)
__global__ __launch_bounds__(256) void k_edge_gather(const u16* __restrict__ Ah,
    const u16* __restrict__ Bh, const float* __restrict__ x,
    const u16* __restrict__ xh, const int* __restrict__ off,
    const u16* __restrict__ eidx, const int* __restrict__ epos,
    const float* __restrict__ w2, const float* __restrict__ b2,
    float* __restrict__ out, int accumulate,
    const float* __restrict__ eps, int layer, float* __restrict__ t)
{
    const int wid = (blockIdx.x * 256 + threadIdx.x) >> 6;
    const int lane = threadIdx.x & 63;
    const int q = lane >> 4, l = lane & 15;
    const int start = wid ? off[wid - 1] : 0;
    const int end = off[wid];
    const uint4 bb = *reinterpret_cast<const uint4*>(Bh + (size_t)wid * HID + l * 8);
    float b8[8] = {bf2f(bb.x & 0xffff), bf2f(bb.x >> 16),
                   bf2f(bb.y & 0xffff), bf2f(bb.y >> 16),
                   bf2f(bb.z & 0xffff), bf2f(bb.z >> 16),
                   bf2f(bb.w & 0xffff), bf2f(bb.w >> 16)};
    float w2f[16];
    #pragma unroll
    for (int tt = 0; tt < 4; ++tt)
        *reinterpret_cast<float4*>(&w2f[tt * 4]) =
            *reinterpret_cast<const float4*>(w2 + l * 16 + tt * 4);
    const float bias0 = b2[0], bias1 = b2[1];
    float g8[8] = {0.f, 0.f, 0.f, 0.f, 0.f, 0.f, 0.f, 0.f};

    #define EG_BODY(EE)                                                        \
    {                                                                          \
        int s = eidx[EE];                                                      \
        const uint4 aa = *reinterpret_cast<const uint4*>(Ah + (size_t)s * HID + l * 8);\
        const uint4 gv = *reinterpret_cast<const uint4*>(xh + (size_t)s * HID + l * 8);\
        g8[0] += bf2f(gv.x & 0xffff); g8[1] += bf2f(gv.x >> 16);               \
        g8[2] += bf2f(gv.y & 0xffff); g8[3] += bf2f(gv.y >> 16);               \
        g8[4] += bf2f(gv.z & 0xffff); g8[5] += bf2f(gv.z >> 16);               \
        g8[6] += bf2f(gv.w & 0xffff); g8[7] += bf2f(gv.w >> 16);               \
        float a8[8] = {bf2f(aa.x & 0xffff), bf2f(aa.x >> 16),                  \
                       bf2f(aa.y & 0xffff), bf2f(aa.y >> 16),                  \
                       bf2f(aa.z & 0xffff), bf2f(aa.z >> 16),                  \
                       bf2f(aa.w & 0xffff), bf2f(aa.w >> 16)};                 \
        float s0 = 0.f, s1 = 0.f;                                              \
        _Pragma("unroll")                                                      \
        for (int j = 0; j < 8; ++j) {                                          \
            float z = fmaxf(a8[j] + b8[j], 0.f);                               \
            s0 = fmaf(z, w2f[j * 2], s0);                                      \
            s1 = fmaf(z, w2f[j * 2 + 1], s1);                                  \
        }                                                                      \
        _Pragma("unroll")                                                      \
        for (int m = 8; m >= 1; m >>= 1) {                                     \
            s0 += __shfl_xor(s0, m);                                           \
            s1 += __shfl_xor(s1, m);                                           \
        }                                                                      \
        if (l == 0) {                                                          \
            int oe = epos[EE];                                                 \
            float o0 = s0 + bias0, o1 = s1 + bias1;                            \
            if (accumulate) { out[oe * 2] += o0; out[oe * 2 + 1] += o1; }      \
            else            { out[oe * 2]  = o0; out[oe * 2 + 1]  = o1; }      \
        }                                                                      \
    }

    int e = start + q;
    for (; e + 12 < end; e += 16) {
        EG_BODY(e) EG_BODY(e + 4) EG_BODY(e + 8) EG_BODY(e + 12)
    }
    for (; e < end; e += 4) EG_BODY(e)
    #undef EG_BODY

    // combine the 4 groups' gather partials: lanes {l, l+16, l+32, l+48}
    #pragma unroll
    for (int j = 0; j < 8; ++j) {
        g8[j] += __shfl_xor(g8[j], 16);
        g8[j] += __shfl_xor(g8[j], 32);
    }
    if (q == 0) {
        const float e1 = 1.0f + eps[layer];
        const float4* xr = reinterpret_cast<const float4*>(x + (size_t)wid * HID + l * 8);
        float4 a0 = xr[0], a1 = xr[1];
        float4* tw = reinterpret_cast<float4*>(t + (size_t)wid * HID + l * 8);
        tw[0] = make_float4(fmaf(a0.x, e1, g8[0]), fmaf(a0.y, e1, g8[1]),
                            fmaf(a0.z, e1, g8[2]), fmaf(a0.w, e1, g8[3]));
        tw[1] = make_float4(fmaf(a1.x, e1, g8[4]), fmaf(a1.y, e1, g8[5]),
                            fmaf(a1.z, e1, g8[6]), fmaf(a1.w, e1, g8[7]));
    }
}

// ---------------------------------------------------------------- launch
extern "C" void kernel_launch(void* const* d_in, const int* in_sizes, int n_in,
                              void* d_out, int out_size, void* d_ws, size_t ws_size,
                              hipStream_t stream)
{
    const float* h        = (const float*)d_in[0];
    const int*   src      = (const int*)d_in[1];
    const int*   dst      = (const int*)d_in[2];
    const float* emb_w    = (const float*)d_in[3];
    const float* emb_b    = (const float*)d_in[4];
    const float* eps      = (const float*)d_in[5];
    const float* mlp_w1   = (const float*)d_in[6];
    const float* mlp_b1   = (const float*)d_in[7];
    const float* mlp_bn_g = (const float*)d_in[8];
    const float* mlp_bn_b = (const float*)d_in[9];
    const float* mlp_w2   = (const float*)d_in[10];
    const float* mlp_b2   = (const float*)d_in[11];
    const float* app_bn_g = (const float*)d_in[12];
    const float* app_bn_b = (const float*)d_in[13];
    const float* gin_bn_g = (const float*)d_in[14];
    const float* gin_bn_b = (const float*)d_in[15];
    const float* pred_w1  = (const float*)d_in[16];
    const float* pred_b1  = (const float*)d_in[17];
    const float* pred_w2  = (const float*)d_in[18];
    const float* pred_b2  = (const float*)d_in[19];
    float* out = (float*)d_out;

    float* ws   = (float*)d_ws;
    float* x    = ws;                       // [N,128] f32
    float* tmp1 = ws + NH;                  // [N,128] f32 (t / v)
    float* tmp2 = ws + 2 * (size_t)NH;      // [N,128] f32 (u), aliased by bf16 A,B
    float* sums = ws + 3 * (size_t)NH;      // [12][256]
    int*   off  = (int*)(sums + 12 * 256);  // [N]
    int*   deg  = off + NNODES;             // [N]
    int*   epos = deg + NNODES;             // [E]
    u16*   eidx = (u16*)(epos + NEDGES);    // [E]
    u16*   ah   = (u16*)tmp2;               // [N,128] bf16
    u16*   bh   = ah + NH;                  // [N,128] bf16
    u16*   xh   = eidx + NEDGES;            // [N,128] bf16 shadow of x
    u16*   wt   = xh + NH;                  // [5][2][128][128] bf16 head weights^T
    u16*   wtm  = wt + 5 * 2 * 128 * 128;   // [4][2][128][128] fp16 MLP weights^T

    const int EB = NEDGES / 256;                // 1250
    const int HB = NNODES / HROWS;              // 625 (all MFMA GEMMs)
    const int ASB = NNODES / 16;                // 1250
    const int CEB = NNODES / 4;                 // 5000
    const int WTB = 5 * 2 * 128 * 128 / 256;    // 640
    const int WMB = 4 * 2 * 128 * 128 / 256;    // 512
    const int SSB = (NNODES + 255) / 256;       // 79

    // ---- CSR build (+ per-node src sort) + weight transposes (once)
    hipMemsetAsync(deg, 0, NNODES * sizeof(int), stream);
    hipMemsetAsync(sums, 0, 12 * 256 * sizeof(float), stream);
    k_hist<<<EB, 256, 0, stream>>>(dst, deg);
    k_scan<<<1, 1024, 0, stream>>>(deg, off);
    k_fill<<<EB, 256, 0, stream>>>(src, dst, off, eidx, epos);
    k_sortseg<<<SSB, 256, 0, stream>>>(off, eidx, epos);
    k_wt<<<WTB, 256, 0, stream>>>(pred_w1, wt);
    k_wtm<<<WMB, 256, 0, stream>>>(mlp_w1, mlp_w2, wtm);

    // head 0 GEMM (MFMA) with embed fused into staging
    k_gemm_head0<<<HB, 256, 0, stream>>>(h, emb_w, emb_b, x, xh,
                                         wt, pred_b1, ah, bh);

    for (int i = 0; i < NL; ++i) {
        float* s0 = sums + (i * 3 + 0) * 256;
        float* s1 = sums + (i * 3 + 1) * 256;
        float* s2 = sums + (i * 3 + 2) * 256;

        // merged: edge scores for head i  +  t = (1+eps)x + sum xh[src]
        k_edge_gather<<<CEB, 256, 0, stream>>>(ah, bh, x, xh, off, eidx, epos,
                                               pred_w2 + i * HID * 2,
                                               pred_b2 + i * 2, out, (i > 0),
                                               eps, i, tmp1);

        // u = t @ W1 + b1 ; stats(u) -> s0   (fp16 MFMA)
        k_mfma_stat<<<HB, 256, 0, stream>>>(tmp1, wtm + (size_t)(i * 2 + 0) * 16384,
                                            mlp_b1 + i * HID, tmp2, s0);
        // v = relu(BN_s0(u)) @ W2 + b2 ; stats(v) -> s1   (fp16 MFMA)
        k_mfma_bnin_stat<<<HB, 256, 0, stream>>>(tmp2, s0, mlp_bn_g + i * HID,
                                                 mlp_bn_b + i * HID,
                                                 wtm + (size_t)(i * 2 + 1) * 16384,
                                                 mlp_b2 + i * HID, tmp1, s1);
        // stats(relu(BN_s1(v))) -> s2
        k_app_stat<<<ASB, 256, 0, stream>>>(tmp1, s1, app_bn_g + i * HID,
                                            app_bn_b + i * HID, s2);
        // x += relu(BN_s2(relu(BN_s1(v)))) fused into MFMA head GEMM staging
        k_head_resid<<<HB, 256, 0, stream>>>(tmp1, s1, app_bn_g + i * HID,
                                             app_bn_b + i * HID, s2,
                                             gin_bn_g + i * HID, gin_bn_b + i * HID,
                                             x, xh,
                                             wt + (size_t)(i + 1) * 2 * 128 * 128,
                                             pred_b1 + (i + 1) * HID, ah, bh);
    }
    // last head's edge scores
    k_edge_csr<<<CEB, 256, 0, stream>>>(ah, bh, off, eidx, epos,
                                        pred_w2 + NL * HID * 2,
                                        pred_b2 + NL * 2, out, 1);
}

// Round 14
// 743.440 us; speedup vs baseline: 1.1364x; 1.1364x over previous
//
#include <hip/hip_runtime.h>

#define NNODES 20000
#define NEDGES 320000
#define HID 128
#define NL 4

constexpr int NH = NNODES * HID;
#define BN_INV (1.0f / (float)NNODES)
#define HROWS 32         // MFMA GEMM rows/block; 625 blocks

typedef unsigned short u16;
typedef unsigned int u32;
typedef __attribute__((ext_vector_type(8))) short bf16x8;
typedef __attribute__((ext_vector_type(8))) _Float16 f16x8;
typedef __attribute__((ext_vector_type(4))) float f32x4;

// ---------------------------------------------------------------- bf16 utils
__device__ __forceinline__ float bf2f(u32 lo16) {
    union { u32 u; float f; } c; c.u = lo16 << 16; return c.f;
}
__device__ __forceinline__ u16 f2bf(float f) {
    union { float f; u32 u; } c; c.f = f;
    u32 r = c.u + 0x7FFFu + ((c.u >> 16) & 1u);
    return (u16)(r >> 16);
}
__device__ __forceinline__ u32 pack2(float a, float b) {
    return (u32)f2bf(a) | ((u32)f2bf(b) << 16);
}

// ------------------------------------------ one-time bf16 head-weight transpose
__global__ __launch_bounds__(256) void k_wt(const float* __restrict__ pw1,
    u16* __restrict__ wt)
{
    int i = blockIdx.x * 256 + threadIdx.x;          // 640 blocks
    int k = i & 127;
    int c = (i >> 7) & 127;
    int sh = i >> 14;                                // h*2+s
    wt[i] = f2bf(pw1[(size_t)(sh >> 1) * 256 * 128 + (((sh & 1) * 128 + k) << 7) + c]);
}

// ------------------------------------------ one-time fp16 MLP-weight transpose
__global__ __launch_bounds__(256) void k_wtm(const float* __restrict__ w1,
    const float* __restrict__ w2, u16* __restrict__ wtm)
{
    int i = blockIdx.x * 256 + threadIdx.x;          // 512 blocks
    int k = i & 127;
    int c = (i >> 7) & 127;
    int lw = i >> 14;                                // layer*2+which
    const float* wsrc = (lw & 1) ? w2 : w1;
    float v = wsrc[(size_t)(lw >> 1) * 16384 + (k << 7) + c];
    union { _Float16 h; u16 u; } cv; cv.h = (_Float16)v;
    wtm[i] = cv.u;
}

// ---------------------------------------------------------------- CSR build
__global__ __launch_bounds__(256) void k_hist(const int* __restrict__ dst,
    int* __restrict__ deg)
{
    int e = blockIdx.x * 256 + threadIdx.x;
    atomicAdd(&deg[dst[e]], 1);
}

__global__ __launch_bounds__(1024) void k_scan(const int* __restrict__ deg,
    int* __restrict__ off)
{
    __shared__ int part[1024];
    const int t = threadIdx.x;
    const int lo = t * 20, hi = min(lo + 20, NNODES);
    int s = 0;
    for (int i = lo; i < hi; ++i) s += deg[i];
    part[t] = s;
    __syncthreads();
    for (int d = 1; d < 1024; d <<= 1) {
        int v = (t >= d) ? part[t - d] : 0;
        __syncthreads();
        part[t] += v;
        __syncthreads();
    }
    int base = part[t] - s;
    for (int i = lo; i < hi; ++i) { off[i] = base; base += deg[i]; }
}

__global__ __launch_bounds__(256) void k_fill(const int* __restrict__ src,
    const int* __restrict__ dst, int* __restrict__ off,
    u16* __restrict__ eidx, int* __restrict__ epos)
{
    int e = blockIdx.x * 256 + threadIdx.x;
    int p = atomicAdd(&off[dst[e]], 1);
    eidx[p] = (u16)src[e];
    epos[p] = e;
}

// --------------------------------------------- stat helper (k_app_stat)
__device__ __forceinline__ void stat_reduce4(float* s4, float* q4, int j0,
    float* ls, float* lq, float* sums)
{
    const int lane = threadIdx.x & 63;
    #pragma unroll
    for (int c = 0; c < 4; ++c) {
        s4[c] += __shfl_xor(s4[c], 32);
        q4[c] += __shfl_xor(q4[c], 32);
    }
    if (lane < 32) {
        #pragma unroll
        for (int c = 0; c < 4; ++c) {
            atomicAdd(&ls[j0 + c], s4[c]);
            atomicAdd(&lq[j0 + c], q4[c]);
        }
    }
    __syncthreads();
    if (threadIdx.x < 128) {
        atomicAdd(&sums[threadIdx.x], ls[threadIdx.x]);
        atomicAdd(&sums[128 + threadIdx.x], lq[threadIdx.x]);
    }
}

// -------------------------------------- MFMA MLP GEMM core (single matrix)
#define MLP_MFMA_TAIL(wtm16, bias, Cm, sums)                                   \
    {                                                                          \
    const int w = tid >> 6;                                                    \
    const int lane = tid & 63;                                                 \
    const int rt = w >> 1;                                                     \
    const int cg = w & 1;                                                      \
    const int lrow = lane & 15;                                                \
    const int kgrp = lane >> 4;                                                \
    f32x4 acc[4];                                                              \
    _Pragma("unroll")                                                          \
    for (int ct = 0; ct < 4; ++ct) acc[ct] = (f32x4){0.f, 0.f, 0.f, 0.f};      \
    _Pragma("unroll")                                                          \
    for (int ks = 0; ks < 4; ++ks) {                                           \
        f16x8 a = *reinterpret_cast<const f16x8*>(                             \
            &Xs[rt * 16 + lrow][ks * 32 + kgrp * 8]);                          \
        _Pragma("unroll")                                                      \
        for (int ct = 0; ct < 4; ++ct) {                                       \
            int col = (cg * 4 + ct) * 16 + lrow;                               \
            f16x8 b = *reinterpret_cast<const f16x8*>(                         \
                wtm16 + ((size_t)col << 7) + ks * 32 + kgrp * 8);              \
            acc[ct] = __builtin_amdgcn_mfma_f32_16x16x32_f16(a, b, acc[ct], 0, 0, 0);\
        }                                                                      \
    }                                                                          \
    _Pragma("unroll")                                                          \
    for (int ct = 0; ct < 4; ++ct) {                                           \
        int col = (cg * 4 + ct) * 16 + lrow;                                   \
        float bbv = bias[col];                                                 \
        float s = 0.f, q = 0.f;                                                \
        _Pragma("unroll")                                                      \
        for (int r = 0; r < 4; ++r) {                                          \
            float val = acc[ct][r] + bbv;                                      \
            Os[rt * 16 + kgrp * 4 + r][col] = val;                             \
            s += val;                                                          \
            q = fmaf(val, val, q);                                             \
        }                                                                      \
        s += __shfl_xor(s, 16); s += __shfl_xor(s, 32);                        \
        q += __shfl_xor(q, 16); q += __shfl_xor(q, 32);                        \
        if (kgrp == 0) { atomicAdd(&ls[col], s); atomicAdd(&lq[col], q); }     \
    }                                                                          \
    __syncthreads();                                                           \
    _Pragma("unroll")                                                          \
    for (int it = 0; it < 4; ++it) {                                           \
        int f = tid + it * 256;                                                \
        int r = f >> 5, c4 = (f & 31) << 2;                                    \
        *reinterpret_cast<float4*>(Cm + (size_t)(br + r) * HID + c4) =         \
            *reinterpret_cast<const float4*>(&Os[r][c4]);                      \
    }                                                                          \
    if (tid < 128) {                                                           \
        atomicAdd(&sums[tid], ls[tid]);                                        \
        atomicAdd(&sums[128 + tid], lq[tid]);                                  \
    }                                                                          \
    }

// u = t @ W1 + b1 ; stats(u)
__global__ __launch_bounds__(256) void k_mfma_stat(const float* __restrict__ X,
    const u16* __restrict__ wtm, const float* __restrict__ bias,
    float* __restrict__ Cm, float* __restrict__ sums)
{
    __shared__ _Float16 Xs[HROWS][136];
    __shared__ float Os[HROWS][132];
    __shared__ float ls[128], lq[128];
    const int tid = threadIdx.x;
    const int br = blockIdx.x * HROWS;
    if (tid < 128) { ls[tid] = 0.f; lq[tid] = 0.f; }
    #pragma unroll
    for (int it = 0; it < 4; ++it) {
        int f = tid + it * 256;
        int r = f >> 5, kq = (f & 31) << 2;
        float4 v = *reinterpret_cast<const float4*>(X + (size_t)(br + r) * HID + kq);
        union { _Float16 h[4]; uint2 u; } p;
        p.h[0] = (_Float16)v.x; p.h[1] = (_Float16)v.y;
        p.h[2] = (_Float16)v.z; p.h[3] = (_Float16)v.w;
        *reinterpret_cast<uint2*>(&Xs[r][kq]) = p.u;
    }
    __syncthreads();
    const _Float16* wtm16 = reinterpret_cast<const _Float16*>(wtm);
    MLP_MFMA_TAIL(wtm16, bias, Cm, sums)
}

// v = relu(BN_sIn(u)) @ W2 + b2 ; stats(v)
__global__ __launch_bounds__(256) void k_mfma_bnin_stat(const float* __restrict__ X,
    const float* __restrict__ sIn, const float* __restrict__ g, const float* __restrict__ b,
    const u16* __restrict__ wtm, const float* __restrict__ bias,
    float* __restrict__ Cm, float* __restrict__ sums)
{
    __shared__ _Float16 Xs[HROWS][136];
    __shared__ float Os[HROWS][132];
    __shared__ float ac[256];
    __shared__ float ls[128], lq[128];
    const int tid = threadIdx.x;
    const int br = blockIdx.x * HROWS;
    if (tid < 128) {
        float m = sIn[tid] * BN_INV;
        float var = fmaf(-m, m, sIn[128 + tid] * BN_INV);
        float a = g[tid] * rsqrtf(var + 1e-5f);
        ac[tid] = a;
        ac[128 + tid] = fmaf(-m, a, b[tid]);
        ls[tid] = 0.f; lq[tid] = 0.f;
    }
    __syncthreads();
    #pragma unroll
    for (int it = 0; it < 4; ++it) {
        int f = tid + it * 256;
        int r = f >> 5, kq = (f & 31) << 2;
        float4 v = *reinterpret_cast<const float4*>(X + (size_t)(br + r) * HID + kq);
        float t0 = fmaxf(fmaf(ac[kq + 0], v.x, ac[128 + kq + 0]), 0.f);
        float t1 = fmaxf(fmaf(ac[kq + 1], v.y, ac[128 + kq + 1]), 0.f);
        float t2 = fmaxf(fmaf(ac[kq + 2], v.z, ac[128 + kq + 2]), 0.f);
        float t3 = fmaxf(fmaf(ac[kq + 3], v.w, ac[128 + kq + 3]), 0.f);
        union { _Float16 h[4]; uint2 u; } p;
        p.h[0] = (_Float16)t0; p.h[1] = (_Float16)t1;
        p.h[2] = (_Float16)t2; p.h[3] = (_Float16)t3;
        *reinterpret_cast<uint2*>(&Xs[r][kq]) = p.u;
    }
    __syncthreads();
    const _Float16* wtm16 = reinterpret_cast<const _Float16*>(wtm);
    MLP_MFMA_TAIL(wtm16, bias, Cm, sums)
}

// ---------------------------------------------- MFMA head GEMM core (shared)
#define HEAD_MFMA_BODY(wtbase, b1, A, Bm)                                      \
    {                                                                          \
    const int w = tid >> 6;                                                    \
    const int lane = tid & 63;                                                 \
    const int rt = w >> 1;                                                     \
    const int cg = w & 1;                                                      \
    const int lrow = lane & 15;                                                \
    const int kgrp = lane >> 4;                                                \
    const u16* wtA = wtbase;                                                   \
    const u16* wtB = wtbase + 16384;                                           \
    f32x4 accA[4], accB[4];                                                    \
    _Pragma("unroll")                                                          \
    for (int ct = 0; ct < 4; ++ct) {                                           \
        accA[ct] = (f32x4){0.f, 0.f, 0.f, 0.f};                                \
        accB[ct] = (f32x4){0.f, 0.f, 0.f, 0.f};                                \
    }                                                                          \
    _Pragma("unroll")                                                          \
    for (int ks = 0; ks < 4; ++ks) {                                           \
        bf16x8 a = *reinterpret_cast<const bf16x8*>(                           \
            &Xs[rt * 16 + lrow][ks * 32 + kgrp * 8]);                          \
        _Pragma("unroll")                                                      \
        for (int ct = 0; ct < 4; ++ct) {                                       \
            int col = (cg * 4 + ct) * 16 + lrow;                               \
            bf16x8 ba = *reinterpret_cast<const bf16x8*>(                      \
                wtA + ((size_t)col << 7) + ks * 32 + kgrp * 8);                \
            bf16x8 bb = *reinterpret_cast<const bf16x8*>(                      \
                wtB + ((size_t)col << 7) + ks * 32 + kgrp * 8);                \
            accA[ct] = __builtin_amdgcn_mfma_f32_16x16x32_bf16(a, ba, accA[ct], 0, 0, 0);\
            accB[ct] = __builtin_amdgcn_mfma_f32_16x16x32_bf16(a, bb, accB[ct], 0, 0, 0);\
        }                                                                      \
    }                                                                          \
    _Pragma("unroll")                                                          \
    for (int ct = 0; ct < 4; ++ct) {                                           \
        int col = (cg * 4 + ct) * 16 + lrow;                                   \
        float bbv = b1[col];                                                   \
        _Pragma("unroll")                                                      \
        for (int r = 0; r < 4; ++r) {                                          \
            int row = rt * 16 + kgrp * 4 + r;                                  \
            Os[0][row][col] = f2bf(accA[ct][r] + bbv);                         \
            Os[1][row][col] = f2bf(accB[ct][r]);                               \
        }                                                                      \
    }                                                                          \
    __syncthreads();                                                           \
    _Pragma("unroll")                                                          \
    for (int it = 0; it < 4; ++it) {                                           \
        int f = tid + it * 256;        /* 1024 uint4 total */                  \
        int s = f >> 9;                                                        \
        int rem = f & 511;                                                     \
        int r = rem >> 4, c8 = (rem & 15) << 3;                                \
        uint4 vv = *reinterpret_cast<uint4*>(&Os[s][r][c8]);                   \
        u16* dstp = s ? Bm : A;                                                \
        *reinterpret_cast<uint4*>(dstp + (size_t)(br + r) * HID + c8) = vv;    \
    }                                                                          \
    }

// head 0: staging computes embed x = h@emb_w+emb_b, writes x/xh, stages bf16
__global__ __launch_bounds__(256) void k_gemm_head0(const float* __restrict__ h,
    const float* __restrict__ ew, const float* __restrict__ eb,
    float* __restrict__ x, u16* __restrict__ xh,
    const u16* __restrict__ wt, const float* __restrict__ b1,
    u16* __restrict__ A, u16* __restrict__ Bm)
{
    __shared__ u16 Xs[HROWS][136];
    __shared__ u16 Os[2][HROWS][136];
    const int tid = threadIdx.x;
    const int br = blockIdx.x * HROWS;
    #pragma unroll
    for (int it = 0; it < 4; ++it) {
        int f = tid + it * 256;
        int r = f >> 5, cq = (f & 31) << 2;
        int nrow = br + r;
        float2 hv = *reinterpret_cast<const float2*>(h + nrow * 2);
        float4 w0 = *reinterpret_cast<const float4*>(ew + cq);
        float4 w1 = *reinterpret_cast<const float4*>(ew + HID + cq);
        float4 bb = *reinterpret_cast<const float4*>(eb + cq);
        float4 v;
        v.x = fmaf(hv.x, w0.x, fmaf(hv.y, w1.x, bb.x));
        v.y = fmaf(hv.x, w0.y, fmaf(hv.y, w1.y, bb.y));
        v.z = fmaf(hv.x, w0.z, fmaf(hv.y, w1.z, bb.z));
        v.w = fmaf(hv.x, w0.w, fmaf(hv.y, w1.w, bb.w));
        size_t goff = (size_t)nrow * HID + cq;
        *reinterpret_cast<float4*>(x + goff) = v;
        uint2 p = make_uint2(pack2(v.x, v.y), pack2(v.z, v.w));
        *reinterpret_cast<uint2*>(xh + goff) = p;
        *reinterpret_cast<uint2*>(&Xs[r][cq]) = p;
    }
    __syncthreads();
    HEAD_MFMA_BODY(wt, b1, A, Bm)
}

// heads 1..L: staging computes x += relu(gin(relu(app(v)))), writes x (+xh),
// stages updated x as bf16 into LDS, then MFMA dual GEMM.
__global__ __launch_bounds__(256) void k_head_resid(const float* __restrict__ v,
    const float* __restrict__ s1, const float* __restrict__ ga, const float* __restrict__ ba,
    const float* __restrict__ s2, const float* __restrict__ gg, const float* __restrict__ bg,
    float* __restrict__ x, u16* __restrict__ xh,
    const u16* __restrict__ wt, const float* __restrict__ b1,
    u16* __restrict__ A, u16* __restrict__ Bm)
{
    __shared__ u16 Xs[HROWS][136];
    __shared__ u16 Os[2][HROWS][136];
    __shared__ float aca[256], acg[256];
    const int tid = threadIdx.x;
    const int br = blockIdx.x * HROWS;
    if (tid < 128) {
        float m = s1[tid] * BN_INV;
        float var = fmaf(-m, m, s1[128 + tid] * BN_INV);
        float a = ga[tid] * rsqrtf(var + 1e-5f);
        aca[tid] = a;
        aca[128 + tid] = fmaf(-m, a, ba[tid]);
        float m2 = s2[tid] * BN_INV;
        float var2 = fmaf(-m2, m2, s2[128 + tid] * BN_INV);
        float a2 = gg[tid] * rsqrtf(var2 + 1e-5f);
        acg[tid] = a2;
        acg[128 + tid] = fmaf(-m2, a2, bg[tid]);
    }
    __syncthreads();
    #pragma unroll
    for (int it = 0; it < 4; ++it) {
        int f = tid + it * 256;
        int r = f >> 5, kq = (f & 31) << 2;
        size_t goff = (size_t)(br + r) * HID + kq;
        float4 vv = *reinterpret_cast<const float4*>(v + goff);
        float4 xv = *reinterpret_cast<const float4*>(x + goff);
        float t0 = fmaxf(fmaf(aca[kq + 0], vv.x, aca[128 + kq + 0]), 0.f);
        float t1 = fmaxf(fmaf(aca[kq + 1], vv.y, aca[128 + kq + 1]), 0.f);
        float t2 = fmaxf(fmaf(aca[kq + 2], vv.z, aca[128 + kq + 2]), 0.f);
        float t3 = fmaxf(fmaf(aca[kq + 3], vv.w, aca[128 + kq + 3]), 0.f);
        xv.x += fmaxf(fmaf(acg[kq + 0], t0, acg[128 + kq + 0]), 0.f);
        xv.y += fmaxf(fmaf(acg[kq + 1], t1, acg[128 + kq + 1]), 0.f);
        xv.z += fmaxf(fmaf(acg[kq + 2], t2, acg[128 + kq + 2]), 0.f);
        xv.w += fmaxf(fmaf(acg[kq + 3], t3, acg[128 + kq + 3]), 0.f);
        *reinterpret_cast<float4*>(x + goff) = xv;
        uint2 p = make_uint2(pack2(xv.x, xv.y), pack2(xv.z, xv.w));
        *reinterpret_cast<uint2*>(xh + goff) = p;
        *reinterpret_cast<uint2*>(&Xs[r][kq]) = p;
    }
    __syncthreads();
    HEAD_MFMA_BODY(wt, b1, A, Bm)
}

// ------------------------------------- stats of relu(app(v)) -> s2
__global__ __launch_bounds__(256) void k_app_stat(const float* __restrict__ v,
    const float* __restrict__ s1, const float* __restrict__ g, const float* __restrict__ b,
    float* __restrict__ s2)
{
    __shared__ float ac[256];
    __shared__ float ls[128], lq[128];
    const int tid = threadIdx.x;
    if (tid < 128) {
        float m = s1[tid] * BN_INV;
        float var = fmaf(-m, m, s1[128 + tid] * BN_INV);
        float a = g[tid] * rsqrtf(var + 1e-5f);
        ac[tid] = a;
        ac[128 + tid] = fmaf(-m, a, b[tid]);
        ls[tid] = 0.f; lq[tid] = 0.f;
    }
    __syncthreads();
    const int j0 = (tid & 31) * 4;
    const int row0 = blockIdx.x * 16 + (tid >> 5);
    float s4[4] = {0.f, 0.f, 0.f, 0.f}, q4[4] = {0.f, 0.f, 0.f, 0.f};
    #pragma unroll
    for (int rr = 0; rr < 2; ++rr) {
        const float4 v4 = *reinterpret_cast<const float4*>(
            v + (size_t)(row0 + rr * 8) * HID + j0);
        float w[4] = {v4.x, v4.y, v4.z, v4.w};
        #pragma unroll
        for (int c = 0; c < 4; ++c) {
            w[c] = fmaxf(fmaf(ac[j0 + c], w[c], ac[128 + j0 + c]), 0.f);
            s4[c] += w[c];
            q4[c] = fmaf(w[c], w[c], q4[c]);
        }
    }
    stat_reduce4(s4, q4, j0, ls, lq, s2);
}

// ---------------------------------------------------- edge head (dst-CSR)
__global__ __launch_bounds__(256) void k_edge_csr(const u16* __restrict__ Ah,
    const u16* __restrict__ Bh, const int* __restrict__ off,
    const u16* __restrict__ eidx, const int* __restrict__ epos,
    const float* __restrict__ w2, const float* __restrict__ b2,
    float* __restrict__ out, int accumulate)
{
    const int wid = (blockIdx.x * 256 + threadIdx.x) >> 6;
    const int lane = threadIdx.x & 63;
    const int q = lane >> 4, l = lane & 15;
    const int start = wid ? off[wid - 1] : 0;
    const int end = off[wid];
    const uint4 bb = *reinterpret_cast<const uint4*>(Bh + (size_t)wid * HID + l * 8);
    float b8[8] = {bf2f(bb.x & 0xffff), bf2f(bb.x >> 16),
                   bf2f(bb.y & 0xffff), bf2f(bb.y >> 16),
                   bf2f(bb.z & 0xffff), bf2f(bb.z >> 16),
                   bf2f(bb.w & 0xffff), bf2f(bb.w >> 16)};
    float w2f[16];
    #pragma unroll
    for (int t = 0; t < 4; ++t)
        *reinterpret_cast<float4*>(&w2f[t * 4]) =
            *reinterpret_cast<const float4*>(w2 + l * 16 + t * 4);
    const float bias0 = b2[0], bias1 = b2[1];

    #define EC_BODY(EE)                                                        \
    {                                                                          \
        int s = eidx[EE];                                                      \
        const uint4 aa = *reinterpret_cast<const uint4*>(Ah + (size_t)s * HID + l * 8);\
        float a8[8] = {bf2f(aa.x & 0xffff), bf2f(aa.x >> 16),                  \
                       bf2f(aa.y & 0xffff), bf2f(aa.y >> 16),                  \
                       bf2f(aa.z & 0xffff), bf2f(aa.z >> 16),                  \
                       bf2f(aa.w & 0xffff), bf2f(aa.w >> 16)};                 \
        float s0 = 0.f, s1 = 0.f;                                              \
        _Pragma("unroll")                                                      \
        for (int j = 0; j < 8; ++j) {                                          \
            float z = fmaxf(a8[j] + b8[j], 0.f);                               \
            s0 = fmaf(z, w2f[j * 2], s0);                                      \
            s1 = fmaf(z, w2f[j * 2 + 1], s1);                                  \
        }                                                                      \
        _Pragma("unroll")                                                      \
        for (int m = 8; m >= 1; m >>= 1) {                                     \
            s0 += __shfl_xor(s0, m);                                           \
            s1 += __shfl_xor(s1, m);                                           \
        }                                                                      \
        if (l == 0) {                                                          \
            int oe = epos[EE];                                                 \
            float o0 = s0 + bias0, o1 = s1 + bias1;                            \
            if (accumulate) { out[oe * 2] += o0; out[oe * 2 + 1] += o1; }      \
            else            { out[oe * 2]  = o0; out[oe * 2 + 1]  = o1; }      \
        }                                                                      \
    }

    int e = start + q;
    for (; e + 12 < end; e += 16) {
        EC_BODY(e) EC_BODY(e + 4) EC_BODY(e + 8) EC_BODY(e + 12)
    }
    for (; e < end; e += 4) EC_BODY(e)
    #undef EC_BODY
}

// ------------------------- merged edge head + gather (one CSR pass)
__global__ __launch_bounds__(256) void k_edge_gather(const u16* __restrict__ Ah,
    const u16* __restrict__ Bh, const float* __restrict__ x,
    const u16* __restrict__ xh, const int* __restrict__ off,
    const u16* __restrict__ eidx, const int* __restrict__ epos,
    const float* __restrict__ w2, const float* __restrict__ b2,
    float* __restrict__ out, int accumulate,
    const float* __restrict__ eps, int layer, float* __restrict__ t)
{
    const int wid = (blockIdx.x * 256 + threadIdx.x) >> 6;
    const int lane = threadIdx.x & 63;
    const int q = lane >> 4, l = lane & 15;
    const int start = wid ? off[wid - 1] : 0;
    const int end = off[wid];
    const uint4 bb = *reinterpret_cast<const uint4*>(Bh + (size_t)wid * HID + l * 8);
    float b8[8] = {bf2f(bb.x & 0xffff), bf2f(bb.x >> 16),
                   bf2f(bb.y & 0xffff), bf2f(bb.y >> 16),
                   bf2f(bb.z & 0xffff), bf2f(bb.z >> 16),
                   bf2f(bb.w & 0xffff), bf2f(bb.w >> 16)};
    float w2f[16];
    #pragma unroll
    for (int tt = 0; tt < 4; ++tt)
        *reinterpret_cast<float4*>(&w2f[tt * 4]) =
            *reinterpret_cast<const float4*>(w2 + l * 16 + tt * 4);
    const float bias0 = b2[0], bias1 = b2[1];
    float g8[8] = {0.f, 0.f, 0.f, 0.f, 0.f, 0.f, 0.f, 0.f};

    #define EG_BODY(EE)                                                        \
    {                                                                          \
        int s = eidx[EE];                                                      \
        const uint4 aa = *reinterpret_cast<const uint4*>(Ah + (size_t)s * HID + l * 8);\
        const uint4 gv = *reinterpret_cast<const uint4*>(xh + (size_t)s * HID + l * 8);\
        g8[0] += bf2f(gv.x & 0xffff); g8[1] += bf2f(gv.x >> 16);               \
        g8[2] += bf2f(gv.y & 0xffff); g8[3] += bf2f(gv.y >> 16);               \
        g8[4] += bf2f(gv.z & 0xffff); g8[5] += bf2f(gv.z >> 16);               \
        g8[6] += bf2f(gv.w & 0xffff); g8[7] += bf2f(gv.w >> 16);               \
        float a8[8] = {bf2f(aa.x & 0xffff), bf2f(aa.x >> 16),                  \
                       bf2f(aa.y & 0xffff), bf2f(aa.y >> 16),                  \
                       bf2f(aa.z & 0xffff), bf2f(aa.z >> 16),                  \
                       bf2f(aa.w & 0xffff), bf2f(aa.w >> 16)};                 \
        float s0 = 0.f, s1 = 0.f;                                              \
        _Pragma("unroll")                                                      \
        for (int j = 0; j < 8; ++j) {                                          \
            float z = fmaxf(a8[j] + b8[j], 0.f);                               \
            s0 = fmaf(z, w2f[j * 2], s0);                                      \
            s1 = fmaf(z, w2f[j * 2 + 1], s1);                                  \
        }                                                                      \
        _Pragma("unroll")                                                      \
        for (int m = 8; m >= 1; m >>= 1) {                                     \
            s0 += __shfl_xor(s0, m);                                           \
            s1 += __shfl_xor(s1, m);                                           \
        }                                                                      \
        if (l == 0) {                                                          \
            int oe = epos[EE];                                                 \
            float o0 = s0 + bias0, o1 = s1 + bias1;                            \
            if (accumulate) { out[oe * 2] += o0; out[oe * 2 + 1] += o1; }      \
            else            { out[oe * 2]  = o0; out[oe * 2 + 1]  = o1; }      \
        }                                                                      \
    }

    int e = start + q;
    for (; e + 12 < end; e += 16) {
        EG_BODY(e) EG_BODY(e + 4) EG_BODY(e + 8) EG_BODY(e + 12)
    }
    for (; e < end; e += 4) EG_BODY(e)
    #undef EG_BODY

    // combine the 4 groups' gather partials: lanes {l, l+16, l+32, l+48}
    #pragma unroll
    for (int j = 0; j < 8; ++j) {
        g8[j] += __shfl_xor(g8[j], 16);
        g8[j] += __shfl_xor(g8[j], 32);
    }
    if (q == 0) {
        const float e1 = 1.0f + eps[layer];
        const float4* xr = reinterpret_cast<const float4*>(x + (size_t)wid * HID + l * 8);
        float4 a0 = xr[0], a1 = xr[1];
        float4* tw = reinterpret_cast<float4*>(t + (size_t)wid * HID + l * 8);
        tw[0] = make_float4(fmaf(a0.x, e1, g8[0]), fmaf(a0.y, e1, g8[1]),
                            fmaf(a0.z, e1, g8[2]), fmaf(a0.w, e1, g8[3]));
        tw[1] = make_float4(fmaf(a1.x, e1, g8[4]), fmaf(a1.y, e1, g8[5]),
                            fmaf(a1.z, e1, g8[6]), fmaf(a1.w, e1, g8[7]));
    }
}

// ---------------------------------------------------------------- launch
extern "C" void kernel_launch(void* const* d_in, const int* in_sizes, int n_in,
                              void* d_out, int out_size, void* d_ws, size_t ws_size,
                              hipStream_t stream)
{
    const float* h        = (const float*)d_in[0];
    const int*   src      = (const int*)d_in[1];
    const int*   dst      = (const int*)d_in[2];
    const float* emb_w    = (const float*)d_in[3];
    const float* emb_b    = (const float*)d_in[4];
    const float* eps      = (const float*)d_in[5];
    const float* mlp_w1   = (const float*)d_in[6];
    const float* mlp_b1   = (const float*)d_in[7];
    const float* mlp_bn_g = (const float*)d_in[8];
    const float* mlp_bn_b = (const float*)d_in[9];
    const float* mlp_w2   = (const float*)d_in[10];
    const float* mlp_b2   = (const float*)d_in[11];
    const float* app_bn_g = (const float*)d_in[12];
    const float* app_bn_b = (const float*)d_in[13];
    const float* gin_bn_g = (const float*)d_in[14];
    const float* gin_bn_b = (const float*)d_in[15];
    const float* pred_w1  = (const float*)d_in[16];
    const float* pred_b1  = (const float*)d_in[17];
    const float* pred_w2  = (const float*)d_in[18];
    const float* pred_b2  = (const float*)d_in[19];
    float* out = (float*)d_out;

    float* ws   = (float*)d_ws;
    float* x    = ws;                       // [N,128] f32
    float* tmp1 = ws + NH;                  // [N,128] f32 (t / v)
    float* tmp2 = ws + 2 * (size_t)NH;      // [N,128] f32 (u), aliased by bf16 A,B
    float* sums = ws + 3 * (size_t)NH;      // [12][256]
    int*   off  = (int*)(sums + 12 * 256);  // [N]
    int*   deg  = off + NNODES;             // [N]
    int*   epos = deg + NNODES;             // [E]
    u16*   eidx = (u16*)(epos + NEDGES);    // [E]
    u16*   ah   = (u16*)tmp2;               // [N,128] bf16
    u16*   bh   = ah + NH;                  // [N,128] bf16
    u16*   xh   = eidx + NEDGES;            // [N,128] bf16 shadow of x
    u16*   wt   = xh + NH;                  // [5][2][128][128] bf16 head weights^T
    u16*   wtm  = wt + 5 * 2 * 128 * 128;   // [4][2][128][128] fp16 MLP weights^T

    const int EB = NEDGES / 256;                // 1250
    const int HB = NNODES / HROWS;              // 625 (all MFMA GEMMs)
    const int ASB = NNODES / 16;                // 1250
    const int CEB = NNODES / 4;                 // 5000
    const int WTB = 5 * 2 * 128 * 128 / 256;    // 640
    const int WMB = 4 * 2 * 128 * 128 / 256;    // 512

    // ---- CSR build + weight transposes (once)
    hipMemsetAsync(deg, 0, NNODES * sizeof(int), stream);
    hipMemsetAsync(sums, 0, 12 * 256 * sizeof(float), stream);
    k_hist<<<EB, 256, 0, stream>>>(dst, deg);
    k_scan<<<1, 1024, 0, stream>>>(deg, off);
    k_fill<<<EB, 256, 0, stream>>>(src, dst, off, eidx, epos);
    k_wt<<<WTB, 256, 0, stream>>>(pred_w1, wt);
    k_wtm<<<WMB, 256, 0, stream>>>(mlp_w1, mlp_w2, wtm);

    // head 0 GEMM (MFMA) with embed fused into staging
    k_gemm_head0<<<HB, 256, 0, stream>>>(h, emb_w, emb_b, x, xh,
                                         wt, pred_b1, ah, bh);

    for (int i = 0; i < NL; ++i) {
        float* s0 = sums + (i * 3 + 0) * 256;
        float* s1 = sums + (i * 3 + 1) * 256;
        float* s2 = sums + (i * 3 + 2) * 256;

        // merged: edge scores for head i  +  t = (1+eps)x + sum xh[src]
        k_edge_gather<<<CEB, 256, 0, stream>>>(ah, bh, x, xh, off, eidx, epos,
                                               pred_w2 + i * HID * 2,
                                               pred_b2 + i * 2, out, (i > 0),
                                               eps, i, tmp1);

        // u = t @ W1 + b1 ; stats(u) -> s0   (fp16 MFMA)
        k_mfma_stat<<<HB, 256, 0, stream>>>(tmp1, wtm + (size_t)(i * 2 + 0) * 16384,
                                            mlp_b1 + i * HID, tmp2, s0);
        // v = relu(BN_s0(u)) @ W2 + b2 ; stats(v) -> s1   (fp16 MFMA)
        k_mfma_bnin_stat<<<HB, 256, 0, stream>>>(tmp2, s0, mlp_bn_g + i * HID,
                                                 mlp_bn_b + i * HID,
                                                 wtm + (size_t)(i * 2 + 1) * 16384,
                                                 mlp_b2 + i * HID, tmp1, s1);
        // stats(relu(BN_s1(v))) -> s2
        k_app_stat<<<ASB, 256, 0, stream>>>(tmp1, s1, app_bn_g + i * HID,
                                            app_bn_b + i * HID, s2);
        // x += relu(BN_s2(relu(BN_s1(v)))) fused into MFMA head GEMM staging
        k_head_resid<<<HB, 256, 0, stream>>>(tmp1, s1, app_bn_g + i * HID,
                                             app_bn_b + i * HID, s2,
                                             gin_bn_g + i * HID, gin_bn_b + i * HID,
                                             x, xh,
                                             wt + (size_t)(i + 1) * 2 * 128 * 128,
                                             pred_b1 + (i + 1) * HID, ah, bh);
    }
    // last head's edge scores
    k_edge_csr<<<CEB, 256, 0, stream>>>(ah, bh, off, eidx, epos,
                                        pred_w2 + NL * HID * 2,
                                        pred_b2 + NL * 2, out, 1);
}

// Round 15
// 724.801 us; speedup vs baseline: 1.1656x; 1.0257x over previous
//
#include <hip/hip_runtime.h>

#define NNODES 20000
#define NEDGES 320000
#define HID 128
#define NL 4

constexpr int NH = NNODES * HID;
#define BN_INV (1.0f / (float)NNODES)
#define HROWS 32         // MFMA GEMM rows/block; 625 blocks

typedef unsigned short u16;
typedef unsigned int u32;
typedef __attribute__((ext_vector_type(8))) short bf16x8;
typedef __attribute__((ext_vector_type(8))) _Float16 f16x8;
typedef __attribute__((ext_vector_type(4))) float f32x4;

// ---------------------------------------------------------------- bf16 utils
__device__ __forceinline__ float bf2f(u32 lo16) {
    union { u32 u; float f; } c; c.u = lo16 << 16; return c.f;
}
__device__ __forceinline__ u16 f2bf(float f) {
    union { float f; u32 u; } c; c.f = f;
    u32 r = c.u + 0x7FFFu + ((c.u >> 16) & 1u);
    return (u16)(r >> 16);
}
__device__ __forceinline__ u32 pack2(float a, float b) {
    return (u32)f2bf(a) | ((u32)f2bf(b) << 16);
}

// ------------------------------------------ one-time bf16 head-weight transpose
__global__ __launch_bounds__(256) void k_wt(const float* __restrict__ pw1,
    u16* __restrict__ wt)
{
    int i = blockIdx.x * 256 + threadIdx.x;          // 640 blocks
    int k = i & 127;
    int c = (i >> 7) & 127;
    int sh = i >> 14;                                // h*2+s
    wt[i] = f2bf(pw1[(size_t)(sh >> 1) * 256 * 128 + (((sh & 1) * 128 + k) << 7) + c]);
}

// ------------------------------------------ one-time fp16 MLP-weight transpose
__global__ __launch_bounds__(256) void k_wtm(const float* __restrict__ w1,
    const float* __restrict__ w2, u16* __restrict__ wtm)
{
    int i = blockIdx.x * 256 + threadIdx.x;          // 512 blocks
    int k = i & 127;
    int c = (i >> 7) & 127;
    int lw = i >> 14;                                // layer*2+which
    const float* wsrc = (lw & 1) ? w2 : w1;
    float v = wsrc[(size_t)(lw >> 1) * 16384 + (k << 7) + c];
    union { _Float16 h; u16 u; } cv; cv.h = (_Float16)v;
    wtm[i] = cv.u;
}

// ---------------------------------------------------------------- CSR build
__global__ __launch_bounds__(256) void k_hist(const int* __restrict__ dst,
    int* __restrict__ deg)
{
    int e = blockIdx.x * 256 + threadIdx.x;
    atomicAdd(&deg[dst[e]], 1);
}

__global__ __launch_bounds__(1024) void k_scan(const int* __restrict__ deg,
    int* __restrict__ off)
{
    __shared__ int part[1024];
    const int t = threadIdx.x;
    const int lo = t * 20, hi = min(lo + 20, NNODES);
    int s = 0;
    for (int i = lo; i < hi; ++i) s += deg[i];
    part[t] = s;
    __syncthreads();
    for (int d = 1; d < 1024; d <<= 1) {
        int v = (t >= d) ? part[t - d] : 0;
        __syncthreads();
        part[t] += v;
        __syncthreads();
    }
    int base = part[t] - s;
    for (int i = lo; i < hi; ++i) { off[i] = base; base += deg[i]; }
}

__global__ __launch_bounds__(256) void k_fill(const int* __restrict__ src,
    const int* __restrict__ dst, int* __restrict__ off,
    u16* __restrict__ eidx, int* __restrict__ epos)
{
    int e = blockIdx.x * 256 + threadIdx.x;
    int p = atomicAdd(&off[dst[e]], 1);
    eidx[p] = (u16)src[e];
    epos[p] = e;
}

// --------------------------------------------- stat helper (k_app_stat)
__device__ __forceinline__ void stat_reduce4(float* s4, float* q4, int j0,
    float* ls, float* lq, float* sums)
{
    const int lane = threadIdx.x & 63;
    #pragma unroll
    for (int c = 0; c < 4; ++c) {
        s4[c] += __shfl_xor(s4[c], 32);
        q4[c] += __shfl_xor(q4[c], 32);
    }
    if (lane < 32) {
        #pragma unroll
        for (int c = 0; c < 4; ++c) {
            atomicAdd(&ls[j0 + c], s4[c]);
            atomicAdd(&lq[j0 + c], q4[c]);
        }
    }
    __syncthreads();
    if (threadIdx.x < 128) {
        atomicAdd(&sums[threadIdx.x], ls[threadIdx.x]);
        atomicAdd(&sums[128 + threadIdx.x], lq[threadIdx.x]);
    }
}

// -------------------------------------- MFMA MLP GEMM core (single matrix)
#define MLP_MFMA_TAIL(wtm16, bias, Cm, sums)                                   \
    {                                                                          \
    const int w = tid >> 6;                                                    \
    const int lane = tid & 63;                                                 \
    const int rt = w >> 1;                                                     \
    const int cg = w & 1;                                                      \
    const int lrow = lane & 15;                                                \
    const int kgrp = lane >> 4;                                                \
    f32x4 acc[4];                                                              \
    _Pragma("unroll")                                                          \
    for (int ct = 0; ct < 4; ++ct) acc[ct] = (f32x4){0.f, 0.f, 0.f, 0.f};      \
    _Pragma("unroll")                                                          \
    for (int ks = 0; ks < 4; ++ks) {                                           \
        f16x8 a = *reinterpret_cast<const f16x8*>(                             \
            &Xs[rt * 16 + lrow][ks * 32 + kgrp * 8]);                          \
        _Pragma("unroll")                                                      \
        for (int ct = 0; ct < 4; ++ct) {                                       \
            int col = (cg * 4 + ct) * 16 + lrow;                               \
            f16x8 b = *reinterpret_cast<const f16x8*>(                         \
                wtm16 + ((size_t)col << 7) + ks * 32 + kgrp * 8);              \
            acc[ct] = __builtin_amdgcn_mfma_f32_16x16x32_f16(a, b, acc[ct], 0, 0, 0);\
        }                                                                      \
    }                                                                          \
    _Pragma("unroll")                                                          \
    for (int ct = 0; ct < 4; ++ct) {                                           \
        int col = (cg * 4 + ct) * 16 + lrow;                                   \
        float bbv = bias[col];                                                 \
        float s = 0.f, q = 0.f;                                                \
        _Pragma("unroll")                                                      \
        for (int r = 0; r < 4; ++r) {                                          \
            float val = acc[ct][r] + bbv;                                      \
            Os[rt * 16 + kgrp * 4 + r][col] = val;                             \
            s += val;                                                          \
            q = fmaf(val, val, q);                                             \
        }                                                                      \
        s += __shfl_xor(s, 16); s += __shfl_xor(s, 32);                        \
        q += __shfl_xor(q, 16); q += __shfl_xor(q, 32);                        \
        if (kgrp == 0) { atomicAdd(&ls[col], s); atomicAdd(&lq[col], q); }     \
    }                                                                          \
    __syncthreads();                                                           \
    _Pragma("unroll")                                                          \
    for (int it = 0; it < 4; ++it) {                                           \
        int f = tid + it * 256;                                                \
        int r = f >> 5, c4 = (f & 31) << 2;                                    \
        *reinterpret_cast<float4*>(Cm + (size_t)(br + r) * HID + c4) =         \
            *reinterpret_cast<const float4*>(&Os[r][c4]);                      \
    }                                                                          \
    if (tid < 128) {                                                           \
        atomicAdd(&sums[tid], ls[tid]);                                        \
        atomicAdd(&sums[128 + tid], lq[tid]);                                  \
    }                                                                          \
    }

// u = t @ W1 + b1 ; stats(u)
__global__ __launch_bounds__(256) void k_mfma_stat(const float* __restrict__ X,
    const u16* __restrict__ wtm, const float* __restrict__ bias,
    float* __restrict__ Cm, float* __restrict__ sums)
{
    __shared__ _Float16 Xs[HROWS][136];
    __shared__ float Os[HROWS][132];
    __shared__ float ls[128], lq[128];
    const int tid = threadIdx.x;
    const int br = blockIdx.x * HROWS;
    if (tid < 128) { ls[tid] = 0.f; lq[tid] = 0.f; }
    #pragma unroll
    for (int it = 0; it < 4; ++it) {
        int f = tid + it * 256;
        int r = f >> 5, kq = (f & 31) << 2;
        float4 v = *reinterpret_cast<const float4*>(X + (size_t)(br + r) * HID + kq);
        union { _Float16 h[4]; uint2 u; } p;
        p.h[0] = (_Float16)v.x; p.h[1] = (_Float16)v.y;
        p.h[2] = (_Float16)v.z; p.h[3] = (_Float16)v.w;
        *reinterpret_cast<uint2*>(&Xs[r][kq]) = p.u;
    }
    __syncthreads();
    const _Float16* wtm16 = reinterpret_cast<const _Float16*>(wtm);
    MLP_MFMA_TAIL(wtm16, bias, Cm, sums)
}

// v = relu(BN_sIn(u)) @ W2 + b2 ; stats(v)
__global__ __launch_bounds__(256) void k_mfma_bnin_stat(const float* __restrict__ X,
    const float* __restrict__ sIn, const float* __restrict__ g, const float* __restrict__ b,
    const u16* __restrict__ wtm, const float* __restrict__ bias,
    float* __restrict__ Cm, float* __restrict__ sums)
{
    __shared__ _Float16 Xs[HROWS][136];
    __shared__ float Os[HROWS][132];
    __shared__ float ac[256];
    __shared__ float ls[128], lq[128];
    const int tid = threadIdx.x;
    const int br = blockIdx.x * HROWS;
    if (tid < 128) {
        float m = sIn[tid] * BN_INV;
        float var = fmaf(-m, m, sIn[128 + tid] * BN_INV);
        float a = g[tid] * rsqrtf(var + 1e-5f);
        ac[tid] = a;
        ac[128 + tid] = fmaf(-m, a, b[tid]);
        ls[tid] = 0.f; lq[tid] = 0.f;
    }
    __syncthreads();
    #pragma unroll
    for (int it = 0; it < 4; ++it) {
        int f = tid + it * 256;
        int r = f >> 5, kq = (f & 31) << 2;
        float4 v = *reinterpret_cast<const float4*>(X + (size_t)(br + r) * HID + kq);
        float t0 = fmaxf(fmaf(ac[kq + 0], v.x, ac[128 + kq + 0]), 0.f);
        float t1 = fmaxf(fmaf(ac[kq + 1], v.y, ac[128 + kq + 1]), 0.f);
        float t2 = fmaxf(fmaf(ac[kq + 2], v.z, ac[128 + kq + 2]), 0.f);
        float t3 = fmaxf(fmaf(ac[kq + 3], v.w, ac[128 + kq + 3]), 0.f);
        union { _Float16 h[4]; uint2 u; } p;
        p.h[0] = (_Float16)t0; p.h[1] = (_Float16)t1;
        p.h[2] = (_Float16)t2; p.h[3] = (_Float16)t3;
        *reinterpret_cast<uint2*>(&Xs[r][kq]) = p.u;
    }
    __syncthreads();
    const _Float16* wtm16 = reinterpret_cast<const _Float16*>(wtm);
    MLP_MFMA_TAIL(wtm16, bias, Cm, sums)
}

// ---------------------------------------------- MFMA head GEMM core (shared)
#define HEAD_MFMA_BODY(wtbase, b1, A, Bm)                                      \
    {                                                                          \
    const int w = tid >> 6;                                                    \
    const int lane = tid & 63;                                                 \
    const int rt = w >> 1;                                                     \
    const int cg = w & 1;                                                      \
    const int lrow = lane & 15;                                                \
    const int kgrp = lane >> 4;                                                \
    const u16* wtA = wtbase;                                                   \
    const u16* wtB = wtbase + 16384;                                           \
    f32x4 accA[4], accB[4];                                                    \
    _Pragma("unroll")                                                          \
    for (int ct = 0; ct < 4; ++ct) {                                           \
        accA[ct] = (f32x4){0.f, 0.f, 0.f, 0.f};                                \
        accB[ct] = (f32x4){0.f, 0.f, 0.f, 0.f};                                \
    }                                                                          \
    _Pragma("unroll")                                                          \
    for (int ks = 0; ks < 4; ++ks) {                                           \
        bf16x8 a = *reinterpret_cast<const bf16x8*>(                           \
            &Xs[rt * 16 + lrow][ks * 32 + kgrp * 8]);                          \
        _Pragma("unroll")                                                      \
        for (int ct = 0; ct < 4; ++ct) {                                       \
            int col = (cg * 4 + ct) * 16 + lrow;                               \
            bf16x8 ba = *reinterpret_cast<const bf16x8*>(                      \
                wtA + ((size_t)col << 7) + ks * 32 + kgrp * 8);                \
            bf16x8 bb = *reinterpret_cast<const bf16x8*>(                      \
                wtB + ((size_t)col << 7) + ks * 32 + kgrp * 8);                \
            accA[ct] = __builtin_amdgcn_mfma_f32_16x16x32_bf16(a, ba, accA[ct], 0, 0, 0);\
            accB[ct] = __builtin_amdgcn_mfma_f32_16x16x32_bf16(a, bb, accB[ct], 0, 0, 0);\
        }                                                                      \
    }                                                                          \
    _Pragma("unroll")                                                          \
    for (int ct = 0; ct < 4; ++ct) {                                           \
        int col = (cg * 4 + ct) * 16 + lrow;                                   \
        float bbv = b1[col];                                                   \
        _Pragma("unroll")                                                      \
        for (int r = 0; r < 4; ++r) {                                          \
            int row = rt * 16 + kgrp * 4 + r;                                  \
            Os[0][row][col] = f2bf(accA[ct][r] + bbv);                         \
            Os[1][row][col] = f2bf(accB[ct][r]);                               \
        }                                                                      \
    }                                                                          \
    __syncthreads();                                                           \
    _Pragma("unroll")                                                          \
    for (int it = 0; it < 4; ++it) {                                           \
        int f = tid + it * 256;        /* 1024 uint4 total */                  \
        int s = f >> 9;                                                        \
        int rem = f & 511;                                                     \
        int r = rem >> 4, c8 = (rem & 15) << 3;                                \
        uint4 vv = *reinterpret_cast<uint4*>(&Os[s][r][c8]);                   \
        u16* dstp = s ? Bm : A;                                                \
        *reinterpret_cast<uint4*>(dstp + (size_t)(br + r) * HID + c8) = vv;    \
    }                                                                          \
    }

// head 0: staging computes embed x = h@emb_w+emb_b, writes x/xh, stages bf16
__global__ __launch_bounds__(256) void k_gemm_head0(const float* __restrict__ h,
    const float* __restrict__ ew, const float* __restrict__ eb,
    float* __restrict__ x, u16* __restrict__ xh,
    const u16* __restrict__ wt, const float* __restrict__ b1,
    u16* __restrict__ A, u16* __restrict__ Bm)
{
    __shared__ u16 Xs[HROWS][136];
    __shared__ u16 Os[2][HROWS][136];
    const int tid = threadIdx.x;
    const int br = blockIdx.x * HROWS;
    #pragma unroll
    for (int it = 0; it < 4; ++it) {
        int f = tid + it * 256;
        int r = f >> 5, cq = (f & 31) << 2;
        int nrow = br + r;
        float2 hv = *reinterpret_cast<const float2*>(h + nrow * 2);
        float4 w0 = *reinterpret_cast<const float4*>(ew + cq);
        float4 w1 = *reinterpret_cast<const float4*>(ew + HID + cq);
        float4 bb = *reinterpret_cast<const float4*>(eb + cq);
        float4 v;
        v.x = fmaf(hv.x, w0.x, fmaf(hv.y, w1.x, bb.x));
        v.y = fmaf(hv.x, w0.y, fmaf(hv.y, w1.y, bb.y));
        v.z = fmaf(hv.x, w0.z, fmaf(hv.y, w1.z, bb.z));
        v.w = fmaf(hv.x, w0.w, fmaf(hv.y, w1.w, bb.w));
        size_t goff = (size_t)nrow * HID + cq;
        *reinterpret_cast<float4*>(x + goff) = v;
        uint2 p = make_uint2(pack2(v.x, v.y), pack2(v.z, v.w));
        *reinterpret_cast<uint2*>(xh + goff) = p;
        *reinterpret_cast<uint2*>(&Xs[r][cq]) = p;
    }
    __syncthreads();
    HEAD_MFMA_BODY(wt, b1, A, Bm)
}

// heads 1..L: staging computes x += relu(gin(relu(app(v)))), writes x (+xh),
// stages updated x as bf16 into LDS, then MFMA dual GEMM.
__global__ __launch_bounds__(256) void k_head_resid(const float* __restrict__ v,
    const float* __restrict__ s1, const float* __restrict__ ga, const float* __restrict__ ba,
    const float* __restrict__ s2, const float* __restrict__ gg, const float* __restrict__ bg,
    float* __restrict__ x, u16* __restrict__ xh,
    const u16* __restrict__ wt, const float* __restrict__ b1,
    u16* __restrict__ A, u16* __restrict__ Bm)
{
    __shared__ u16 Xs[HROWS][136];
    __shared__ u16 Os[2][HROWS][136];
    __shared__ float aca[256], acg[256];
    const int tid = threadIdx.x;
    const int br = blockIdx.x * HROWS;
    if (tid < 128) {
        float m = s1[tid] * BN_INV;
        float var = fmaf(-m, m, s1[128 + tid] * BN_INV);
        float a = ga[tid] * rsqrtf(var + 1e-5f);
        aca[tid] = a;
        aca[128 + tid] = fmaf(-m, a, ba[tid]);
        float m2 = s2[tid] * BN_INV;
        float var2 = fmaf(-m2, m2, s2[128 + tid] * BN_INV);
        float a2 = gg[tid] * rsqrtf(var2 + 1e-5f);
        acg[tid] = a2;
        acg[128 + tid] = fmaf(-m2, a2, bg[tid]);
    }
    __syncthreads();
    #pragma unroll
    for (int it = 0; it < 4; ++it) {
        int f = tid + it * 256;
        int r = f >> 5, kq = (f & 31) << 2;
        size_t goff = (size_t)(br + r) * HID + kq;
        float4 vv = *reinterpret_cast<const float4*>(v + goff);
        float4 xv = *reinterpret_cast<const float4*>(x + goff);
        float t0 = fmaxf(fmaf(aca[kq + 0], vv.x, aca[128 + kq + 0]), 0.f);
        float t1 = fmaxf(fmaf(aca[kq + 1], vv.y, aca[128 + kq + 1]), 0.f);
        float t2 = fmaxf(fmaf(aca[kq + 2], vv.z, aca[128 + kq + 2]), 0.f);
        float t3 = fmaxf(fmaf(aca[kq + 3], vv.w, aca[128 + kq + 3]), 0.f);
        xv.x += fmaxf(fmaf(acg[kq + 0], t0, acg[128 + kq + 0]), 0.f);
        xv.y += fmaxf(fmaf(acg[kq + 1], t1, acg[128 + kq + 1]), 0.f);
        xv.z += fmaxf(fmaf(acg[kq + 2], t2, acg[128 + kq + 2]), 0.f);
        xv.w += fmaxf(fmaf(acg[kq + 3], t3, acg[128 + kq + 3]), 0.f);
        *reinterpret_cast<float4*>(x + goff) = xv;
        uint2 p = make_uint2(pack2(xv.x, xv.y), pack2(xv.z, xv.w));
        *reinterpret_cast<uint2*>(xh + goff) = p;
        *reinterpret_cast<uint2*>(&Xs[r][kq]) = p;
    }
    __syncthreads();
    HEAD_MFMA_BODY(wt, b1, A, Bm)
}

// ------------------------------------- stats of relu(app(v)) -> s2
__global__ __launch_bounds__(256) void k_app_stat(const float* __restrict__ v,
    const float* __restrict__ s1, const float* __restrict__ g, const float* __restrict__ b,
    float* __restrict__ s2)
{
    __shared__ float ac[256];
    __shared__ float ls[128], lq[128];
    const int tid = threadIdx.x;
    if (tid < 128) {
        float m = s1[tid] * BN_INV;
        float var = fmaf(-m, m, s1[128 + tid] * BN_INV);
        float a = g[tid] * rsqrtf(var + 1e-5f);
        ac[tid] = a;
        ac[128 + tid] = fmaf(-m, a, b[tid]);
        ls[tid] = 0.f; lq[tid] = 0.f;
    }
    __syncthreads();
    const int j0 = (tid & 31) * 4;
    const int row0 = blockIdx.x * 16 + (tid >> 5);
    float s4[4] = {0.f, 0.f, 0.f, 0.f}, q4[4] = {0.f, 0.f, 0.f, 0.f};
    #pragma unroll
    for (int rr = 0; rr < 2; ++rr) {
        const float4 v4 = *reinterpret_cast<const float4*>(
            v + (size_t)(row0 + rr * 8) * HID + j0);
        float w[4] = {v4.x, v4.y, v4.z, v4.w};
        #pragma unroll
        for (int c = 0; c < 4; ++c) {
            w[c] = fmaxf(fmaf(ac[j0 + c], w[c], ac[128 + j0 + c]), 0.f);
            s4[c] += w[c];
            q4[c] = fmaf(w[c], w[c], q4[c]);
        }
    }
    stat_reduce4(s4, q4, j0, ls, lq, s2);
}

// ---------------------------------------------------- edge head (dst-CSR)
__global__ __launch_bounds__(256) void k_edge_csr(const u16* __restrict__ Ah,
    const u16* __restrict__ Bh, const int* __restrict__ off,
    const u16* __restrict__ eidx, const int* __restrict__ epos,
    const float* __restrict__ w2, const float* __restrict__ b2,
    float* __restrict__ out, int accumulate)
{
    const int wid = (blockIdx.x * 256 + threadIdx.x) >> 6;
    const int lane = threadIdx.x & 63;
    const int q = lane >> 4, l = lane & 15;
    const int start = wid ? off[wid - 1] : 0;
    const int end = off[wid];
    const uint4 bb = *reinterpret_cast<const uint4*>(Bh + (size_t)wid * HID + l * 8);
    float b8[8] = {bf2f(bb.x & 0xffff), bf2f(bb.x >> 16),
                   bf2f(bb.y & 0xffff), bf2f(bb.y >> 16),
                   bf2f(bb.z & 0xffff), bf2f(bb.z >> 16),
                   bf2f(bb.w & 0xffff), bf2f(bb.w >> 16)};
    float w2f[16];
    #pragma unroll
    for (int t = 0; t < 4; ++t)
        *reinterpret_cast<float4*>(&w2f[t * 4]) =
            *reinterpret_cast<const float4*>(w2 + l * 16 + t * 4);
    const float bias0 = b2[0], bias1 = b2[1];
    for (int e = start + q; e < end; e += 4) {
        int s = eidx[e];
        const uint4 aa = *reinterpret_cast<const uint4*>(Ah + (size_t)s * HID + l * 8);
        float a8[8] = {bf2f(aa.x & 0xffff), bf2f(aa.x >> 16),
                       bf2f(aa.y & 0xffff), bf2f(aa.y >> 16),
                       bf2f(aa.z & 0xffff), bf2f(aa.z >> 16),
                       bf2f(aa.w & 0xffff), bf2f(aa.w >> 16)};
        float s0 = 0.f, s1 = 0.f;
        #pragma unroll
        for (int j = 0; j < 8; ++j) {
            float z = fmaxf(a8[j] + b8[j], 0.f);
            s0 = fmaf(z, w2f[j * 2], s0);
            s1 = fmaf(z, w2f[j * 2 + 1], s1);
        }
        #pragma unroll
        for (int m = 8; m >= 1; m >>= 1) {
            s0 += __shfl_xor(s0, m);
            s1 += __shfl_xor(s1, m);
        }
        if (l == 0) {
            int oe = epos[e];
            float o0 = s0 + bias0, o1 = s1 + bias1;
            if (accumulate) {
                out[oe * 2 + 0] += o0;
                out[oe * 2 + 1] += o1;
            } else {
                out[oe * 2 + 0] = o0;
                out[oe * 2 + 1] = o1;
            }
        }
    }
}

// ------------------------- merged edge head + gather (one CSR pass)
__global__ __launch_bounds__(256) void k_edge_gather(const u16* __restrict__ Ah,
    const u16* __restrict__ Bh, const float* __restrict__ x,
    const u16* __restrict__ xh, const int* __restrict__ off,
    const u16* __restrict__ eidx, const int* __restrict__ epos,
    const float* __restrict__ w2, const float* __restrict__ b2,
    float* __restrict__ out, int accumulate,
    const float* __restrict__ eps, int layer, float* __restrict__ t)
{
    const int wid = (blockIdx.x * 256 + threadIdx.x) >> 6;
    const int lane = threadIdx.x & 63;
    const int q = lane >> 4, l = lane & 15;
    const int start = wid ? off[wid - 1] : 0;
    const int end = off[wid];
    const uint4 bb = *reinterpret_cast<const uint4*>(Bh + (size_t)wid * HID + l * 8);
    float b8[8] = {bf2f(bb.x & 0xffff), bf2f(bb.x >> 16),
                   bf2f(bb.y & 0xffff), bf2f(bb.y >> 16),
                   bf2f(bb.z & 0xffff), bf2f(bb.z >> 16),
                   bf2f(bb.w & 0xffff), bf2f(bb.w >> 16)};
    float w2f[16];
    #pragma unroll
    for (int tt = 0; tt < 4; ++tt)
        *reinterpret_cast<float4*>(&w2f[tt * 4]) =
            *reinterpret_cast<const float4*>(w2 + l * 16 + tt * 4);
    const float bias0 = b2[0], bias1 = b2[1];
    float g8[8] = {0.f, 0.f, 0.f, 0.f, 0.f, 0.f, 0.f, 0.f};

    #define EG_BODY(EE)                                                        \
    {                                                                          \
        int s = eidx[EE];                                                      \
        const uint4 aa = *reinterpret_cast<const uint4*>(Ah + (size_t)s * HID + l * 8);\
        const uint4 gv = *reinterpret_cast<const uint4*>(xh + (size_t)s * HID + l * 8);\
        g8[0] += bf2f(gv.x & 0xffff); g8[1] += bf2f(gv.x >> 16);               \
        g8[2] += bf2f(gv.y & 0xffff); g8[3] += bf2f(gv.y >> 16);               \
        g8[4] += bf2f(gv.z & 0xffff); g8[5] += bf2f(gv.z >> 16);               \
        g8[6] += bf2f(gv.w & 0xffff); g8[7] += bf2f(gv.w >> 16);               \
        float a8[8] = {bf2f(aa.x & 0xffff), bf2f(aa.x >> 16),                  \
                       bf2f(aa.y & 0xffff), bf2f(aa.y >> 16),                  \
                       bf2f(aa.z & 0xffff), bf2f(aa.z >> 16),                  \
                       bf2f(aa.w & 0xffff), bf2f(aa.w >> 16)};                 \
        float s0 = 0.f, s1 = 0.f;                                              \
        _Pragma("unroll")                                                      \
        for (int j = 0; j < 8; ++j) {                                          \
            float z = fmaxf(a8[j] + b8[j], 0.f);                               \
            s0 = fmaf(z, w2f[j * 2], s0);                                      \
            s1 = fmaf(z, w2f[j * 2 + 1], s1);                                  \
        }                                                                      \
        _Pragma("unroll")                                                      \
        for (int m = 8; m >= 1; m >>= 1) {                                     \
            s0 += __shfl_xor(s0, m);                                           \
            s1 += __shfl_xor(s1, m);                                           \
        }                                                                      \
        if (l == 0) {                                                          \
            int oe = epos[EE];                                                 \
            float o0 = s0 + bias0, o1 = s1 + bias1;                            \
            if (accumulate) { out[oe * 2] += o0; out[oe * 2 + 1] += o1; }      \
            else            { out[oe * 2]  = o0; out[oe * 2 + 1]  = o1; }      \
        }                                                                      \
    }

    int e = start + q;
    for (; e + 4 < end; e += 8) {      // 2 edges in flight per group
        EG_BODY(e)
        EG_BODY(e + 4)
    }
    if (e < end) EG_BODY(e)
    #undef EG_BODY

    // combine the 4 groups' gather partials: lanes {l, l+16, l+32, l+48}
    #pragma unroll
    for (int j = 0; j < 8; ++j) {
        g8[j] += __shfl_xor(g8[j], 16);
        g8[j] += __shfl_xor(g8[j], 32);
    }
    if (q == 0) {
        const float e1 = 1.0f + eps[layer];
        const float4* xr = reinterpret_cast<const float4*>(x + (size_t)wid * HID + l * 8);
        float4 a0 = xr[0], a1 = xr[1];
        float4* tw = reinterpret_cast<float4*>(t + (size_t)wid * HID + l * 8);
        tw[0] = make_float4(fmaf(a0.x, e1, g8[0]), fmaf(a0.y, e1, g8[1]),
                            fmaf(a0.z, e1, g8[2]), fmaf(a0.w, e1, g8[3]));
        tw[1] = make_float4(fmaf(a1.x, e1, g8[4]), fmaf(a1.y, e1, g8[5]),
                            fmaf(a1.z, e1, g8[6]), fmaf(a1.w, e1, g8[7]));
    }
}

// ---------------------------------------------------------------- launch
extern "C" void kernel_launch(void* const* d_in, const int* in_sizes, int n_in,
                              void* d_out, int out_size, void* d_ws, size_t ws_size,
                              hipStream_t stream)
{
    const float* h        = (const float*)d_in[0];
    const int*   src      = (const int*)d_in[1];
    const int*   dst      = (const int*)d_in[2];
    const float* emb_w    = (const float*)d_in[3];
    const float* emb_b    = (const float*)d_in[4];
    const float* eps      = (const float*)d_in[5];
    const float* mlp_w1   = (const float*)d_in[6];
    const float* mlp_b1   = (const float*)d_in[7];
    const float* mlp_bn_g = (const float*)d_in[8];
    const float* mlp_bn_b = (const float*)d_in[9];
    const float* mlp_w2   = (const float*)d_in[10];
    const float* mlp_b2   = (const float*)d_in[11];
    const float* app_bn_g = (const float*)d_in[12];
    const float* app_bn_b = (const float*)d_in[13];
    const float* gin_bn_g = (const float*)d_in[14];
    const float* gin_bn_b = (const float*)d_in[15];
    const float* pred_w1  = (const float*)d_in[16];
    const float* pred_b1  = (const float*)d_in[17];
    const float* pred_w2  = (const float*)d_in[18];
    const float* pred_b2  = (const float*)d_in[19];
    float* out = (float*)d_out;

    float* ws   = (float*)d_ws;
    float* x    = ws;                       // [N,128] f32
    float* tmp1 = ws + NH;                  // [N,128] f32 (t / v)
    float* tmp2 = ws + 2 * (size_t)NH;      // [N,128] f32 (u), aliased by bf16 A,B
    float* sums = ws + 3 * (size_t)NH;      // [12][256]
    int*   off  = (int*)(sums + 12 * 256);  // [N]
    int*   deg  = off + NNODES;             // [N]
    int*   epos = deg + NNODES;             // [E]
    u16*   eidx = (u16*)(epos + NEDGES);    // [E]
    u16*   ah   = (u16*)tmp2;               // [N,128] bf16
    u16*   bh   = ah + NH;                  // [N,128] bf16
    u16*   xh   = eidx + NEDGES;            // [N,128] bf16 shadow of x
    u16*   wt   = xh + NH;                  // [5][2][128][128] bf16 head weights^T
    u16*   wtm  = wt + 5 * 2 * 128 * 128;   // [4][2][128][128] fp16 MLP weights^T

    const int EB = NEDGES / 256;                // 1250
    const int HB = NNODES / HROWS;              // 625 (all MFMA GEMMs)
    const int ASB = NNODES / 16;                // 1250
    const int CEB = NNODES / 4;                 // 5000
    const int WTB = 5 * 2 * 128 * 128 / 256;    // 640
    const int WMB = 4 * 2 * 128 * 128 / 256;    // 512

    // ---- CSR build + weight transposes (once)
    hipMemsetAsync(deg, 0, NNODES * sizeof(int), stream);
    hipMemsetAsync(sums, 0, 12 * 256 * sizeof(float), stream);
    k_hist<<<EB, 256, 0, stream>>>(dst, deg);
    k_scan<<<1, 1024, 0, stream>>>(deg, off);
    k_fill<<<EB, 256, 0, stream>>>(src, dst, off, eidx, epos);
    k_wt<<<WTB, 256, 0, stream>>>(pred_w1, wt);
    k_wtm<<<WMB, 256, 0, stream>>>(mlp_w1, mlp_w2, wtm);

    // head 0 GEMM (MFMA) with embed fused into staging
    k_gemm_head0<<<HB, 256, 0, stream>>>(h, emb_w, emb_b, x, xh,
                                         wt, pred_b1, ah, bh);

    for (int i = 0; i < NL; ++i) {
        float* s0 = sums + (i * 3 + 0) * 256;
        float* s1 = sums + (i * 3 + 1) * 256;
        float* s2 = sums + (i * 3 + 2) * 256;

        // merged: edge scores for head i  +  t = (1+eps)x + sum xh[src]
        k_edge_gather<<<CEB, 256, 0, stream>>>(ah, bh, x, xh, off, eidx, epos,
                                               pred_w2 + i * HID * 2,
                                               pred_b2 + i * 2, out, (i > 0),
                                               eps, i, tmp1);

        // u = t @ W1 + b1 ; stats(u) -> s0   (fp16 MFMA)
        k_mfma_stat<<<HB, 256, 0, stream>>>(tmp1, wtm + (size_t)(i * 2 + 0) * 16384,
                                            mlp_b1 + i * HID, tmp2, s0);
        // v = relu(BN_s0(u)) @ W2 + b2 ; stats(v) -> s1   (fp16 MFMA)
        k_mfma_bnin_stat<<<HB, 256, 0, stream>>>(tmp2, s0, mlp_bn_g + i * HID,
                                                 mlp_bn_b + i * HID,
                                                 wtm + (size_t)(i * 2 + 1) * 16384,
                                                 mlp_b2 + i * HID, tmp1, s1);
        // stats(relu(BN_s1(v))) -> s2
        k_app_stat<<<ASB, 256, 0, stream>>>(tmp1, s1, app_bn_g + i * HID,
                                            app_bn_b + i * HID, s2);
        // x += relu(BN_s2(relu(BN_s1(v)))) fused into MFMA head GEMM staging
        k_head_resid<<<HB, 256, 0, stream>>>(tmp1, s1, app_bn_g + i * HID,
                                             app_bn_b + i * HID, s2,
                                             gin_bn_g + i * HID, gin_bn_b + i * HID,
                                             x, xh,
                                             wt + (size_t)(i + 1) * 2 * 128 * 128,
                                             pred_b1 + (i + 1) * HID, ah, bh);
    }
    // last head's edge scores
    k_edge_csr<<<CEB, 256, 0, stream>>>(ah, bh, off, eidx, epos,
                                        pred_w2 + NL * HID * 2,
                                        pred_b2 + NL * 2, out, 1);
}